// Round 1
// baseline (6525.002 us; speedup 1.0000x reference)
//
#include <hip/hip_runtime.h>
#include <math.h>

// Brute-force KNN (L2, top-32) + cosine re-rank for MI355X.
// Phase 0: row sum-of-squares for cand_emb0 / query_emb0.
// Phase 1: fused distance-GEMM + per-chunk top-32 (4 chunks of 12500 cands).
// Phase 2: exact merge (rank-select over 128) + gather + cosine/max/mean.
// ws usage: ~2.3 MB (c2, q2, partial top-k dists+idx).

#define D      512
#define MT     32     // queries per WG (phase 1)
#define NT     256    // candidates per tile step
#define KC     32     // K chunk
#define TM     8      // queries per thread
#define TN     4      // candidates per thread
#define NTH    256    // threads per block
#define KSEL   32     // k
#define NCHUNKS 4
#define CEPS   1e-8f

// ---------------- Phase 0: row sum-of-squares ----------------
__global__ __launch_bounds__(256) void rows_sumsq_kernel(
    const float* __restrict__ C, const float* __restrict__ Q,
    float* __restrict__ c2, float* __restrict__ q2, int n2, int n1)
{
  int wid  = threadIdx.x >> 6;
  int lane = threadIdx.x & 63;
  int row  = blockIdx.x * 4 + wid;
  const float* src;
  float* dst;
  if (row < n2) { src = C + (size_t)row * D; dst = c2 + row; }
  else {
    int r = row - n2;
    if (r >= n1) return;
    src = Q + (size_t)r * D; dst = q2 + r;
  }
  const float4* s4 = (const float4*)src;
  float4 a = s4[lane];
  float4 b = s4[lane + 64];
  float s = a.x*a.x + a.y*a.y + a.z*a.z + a.w*a.w
          + b.x*b.x + b.y*b.y + b.z*b.z + b.w*b.w;
  #pragma unroll
  for (int o = 32; o > 0; o >>= 1) s += __shfl_down(s, o, 64);
  if (lane == 0) *dst = s;
}

// ---------------- Phase 1: distance GEMM + partial top-k ----------------
__global__ __launch_bounds__(NTH) void knn_phase1_kernel(
    const float* __restrict__ Q, const float* __restrict__ C,
    const float* __restrict__ q2g, const float* __restrict__ c2g,
    float* __restrict__ tkd, int* __restrict__ tki,
    int n1, int n2, int chunk)
{
  extern __shared__ char smem[];
  float* qs  = (float*)smem;                                   // [MT][D]
  float* cs  = (float*)(smem + (size_t)MT*D*4);                // [NT][KC] swizzled
  float* dl  = (float*)(smem + (size_t)MT*D*4 + NT*KC*4);      // [MT][NT+1]
  float* ld  = (float*)((char*)dl + (size_t)MT*(NT+1)*4);      // [MT][33] list dists
  int*   li  = (int*)  ((char*)ld + (size_t)MT*33*4);          // [MT][33] list idx
  float* q2s = (float*)((char*)li + (size_t)MT*33*4);          // [MT]

  const int tid = threadIdx.x;
  const int tn  = tid & 63;   // candidate-group id (64 groups of TN)
  const int tm  = tid >> 6;   // query-group id (4 groups of TM) == wave id
  const int mbase   = blockIdx.x * MT;
  const int chunkid = blockIdx.y;
  const int cbase0  = chunkid * chunk;
  const int cend    = min(cbase0 + chunk, n2);

  // stage queries (MT*D floats = 4096 float4, 16 per thread)
  #pragma unroll
  for (int r = 0; r < (MT*D/4)/NTH; ++r) {
    int f  = tid + NTH * r;
    int m  = f >> 7;          // D/4 = 128 float4 per row
    int qd = f & 127;
    int gm = min(mbase + m, n1 - 1);
    ((float4*)qs)[f] = ((const float4*)(Q + (size_t)gm * D))[qd];
  }
  if (tid < MT) {
    int gm = min(mbase + tid, n1 - 1);
    q2s[tid] = q2g[gm];
    #pragma unroll
    for (int j = 0; j < KSEL; ++j) { ld[tid*33+j] = __builtin_inff(); li[tid*33+j] = 0x7fffffff; }
  }

  float4 vr[8];
  auto LOADR = [&](int kc, int cb) {
    #pragma unroll
    for (int r = 0; r < (NT*KC/4)/NTH; ++r) {   // 8
      int f  = tid + NTH * r;
      int n  = f >> 3;        // KC/4 = 8 quads per row
      int qd = f & 7;
      int gn = cb + n;
      float4 v = make_float4(0.f, 0.f, 0.f, 0.f);
      if (gn < cend) v = *((const float4*)(C + (size_t)gn * D + (size_t)kc * KC) + qd);
      vr[r] = v;
    }
  };
  auto STORE = [&]() {
    #pragma unroll
    for (int r = 0; r < (NT*KC/4)/NTH; ++r) {
      int f  = tid + NTH * r;
      int n  = f >> 3;
      int qd = f & 7;
      int slot = qd ^ ((n >> 2) & 7);           // bank-conflict XOR swizzle
      *((float4*)(cs + (size_t)n * KC) + slot) = vr[r];
    }
  };

  const int nsteps = (chunk + NT - 1) / NT;
  LOADR(0, cbase0);  // prologue prefetch

  for (int nt = 0; nt < nsteps; ++nt) {
    const int cbase = cbase0 + nt * NT;
    float acc[TM][TN] = {};

    for (int kc = 0; kc < D/KC; ++kc) {
      __syncthreads();            // previous tile fully consumed (also fences top-k)
      STORE();
      __syncthreads();
      // issue next stage's global loads; latency hides under the FMA block below
      if (kc + 1 < D/KC)            LOADR(kc + 1, cbase);
      else if (nt + 1 < nsteps)     LOADR(0, cbase + NT);

      float acc2[TM][TN] = {};    // per-K-block partial (accuracy: block summation)
      #pragma unroll
      for (int s = 0; s < KC/4; ++s) {
        float4 qf[TM];
        #pragma unroll
        for (int i = 0; i < TM; ++i)
          qf[i] = *((const float4*)(qs + (size_t)(tm*TM + i)*D + (size_t)kc*KC) + s);
        const int slot = s ^ (tn & 7);
        float4 cf[TN];
        #pragma unroll
        for (int j = 0; j < TN; ++j)
          cf[j] = *((const float4*)(cs + (size_t)(tn*4 + j)*KC) + slot);
        #pragma unroll
        for (int i = 0; i < TM; ++i)
          #pragma unroll
          for (int j = 0; j < TN; ++j) {
            float t = acc2[i][j];
            t = fmaf(qf[i].x, cf[j].x, t);
            t = fmaf(qf[i].y, cf[j].y, t);
            t = fmaf(qf[i].z, cf[j].z, t);
            t = fmaf(qf[i].w, cf[j].w, t);
            acc2[i][j] = t;
          }
      }
      #pragma unroll
      for (int i = 0; i < TM; ++i)
        #pragma unroll
        for (int j = 0; j < TN; ++j) acc[i][j] += acc2[i][j];
    }

    // distances -> dl (padded stride NT+1 to avoid bank conflicts in top-k scan)
    {
      float c2v[TN]; int valid[TN];
      #pragma unroll
      for (int j = 0; j < TN; ++j) {
        int gn = cbase + tn*4 + j;
        valid[j] = (gn < cend);
        c2v[j] = valid[j] ? c2g[gn] : 0.f;
      }
      #pragma unroll
      for (int i = 0; i < TM; ++i) {
        float q2v = q2s[tm*TM + i];
        #pragma unroll
        for (int j = 0; j < TN; ++j) {
          float d2 = q2v + c2v[j] - 2.f * acc[i][j];
          float dv = valid[j] ? sqrtf(fmaxf(d2, 0.f)) : __builtin_inff();
          dl[(size_t)(tm*TM + i)*(NT+1) + tn*4 + j] = dv;
        }
      }
    }
    __syncthreads();

    // serial top-32 maintenance, one lane per query. Candidates arrive in
    // ascending index order -> strict '<' reproduces top_k tie-breaking.
    if (tid < MT) {
      const int m = tid;
      float worst = ld[m*33 + 31];
      for (int c = 0; c < NT; ++c) {
        float dv = dl[(size_t)m*(NT+1) + c];
        if (dv < worst) {
          int pos = 31;
          while (pos > 0 && ld[m*33 + pos - 1] > dv) {
            ld[m*33 + pos] = ld[m*33 + pos - 1];
            li[m*33 + pos] = li[m*33 + pos - 1];
            --pos;
          }
          ld[m*33 + pos] = dv;
          li[m*33 + pos] = cbase + c;
          worst = ld[m*33 + 31];
        }
      }
    }
  }
  __syncthreads();

  // write per-chunk sorted top-32
  for (int t = tid; t < MT*KSEL; t += NTH) {
    int m = t >> 5, j = t & 31;
    int gq = mbase + m;
    if (gq < n1) {
      size_t o = ((size_t)gq * NCHUNKS + chunkid) * KSEL + j;
      tkd[o] = ld[m*33 + j];
      tki[o] = li[m*33 + j];
    }
  }
}

// ---------------- Phase 2: merge + gather + cosine ----------------
__global__ __launch_bounds__(256) void knn_phase2_kernel(
    const float* __restrict__ Q0, const float* __restrict__ Q1,
    const float* __restrict__ C0, const float* __restrict__ C1,
    const float* __restrict__ tkd, const int* __restrict__ tki,
    float* __restrict__ out, int n1)
{
  __shared__ float q0s[D], q1s[D];
  __shared__ float pd[NCHUNKS*KSEL];
  __shared__ int   pi[NCHUNKS*KSEL];
  __shared__ float md[KSEL];
  __shared__ int   mi[KSEL];
  __shared__ float cosj[KSEL];
  __shared__ float red0[4], red1[4];
  __shared__ float qn[2];

  const int q   = blockIdx.x;
  const int tid = threadIdx.x;

  if (tid < 128) {
    ((float4*)q0s)[tid] = ((const float4*)(Q0 + (size_t)q*D))[tid];
    pd[tid] = tkd[(size_t)q*NCHUNKS*KSEL + tid];
    pi[tid] = tki[(size_t)q*NCHUNKS*KSEL + tid];
  } else {
    ((float4*)q1s)[tid-128] = ((const float4*)(Q1 + (size_t)q*D))[tid-128];
  }
  __syncthreads();

  // query norms (block reduce)
  float a0 = q0s[tid], b0 = q0s[tid+256];
  float a1 = q1s[tid], b1 = q1s[tid+256];
  float s0 = a0*a0 + b0*b0;
  float s1 = a1*a1 + b1*b1;
  #pragma unroll
  for (int o = 32; o > 0; o >>= 1) { s0 += __shfl_down(s0, o, 64); s1 += __shfl_down(s1, o, 64); }
  int lane = tid & 63, wid = tid >> 6;
  if (lane == 0) { red0[wid] = s0; red1[wid] = s1; }

  // exact top-32 of the 128 partials via rank selection.
  // compare (dist asc, idx asc) -- reproduces jax.lax.top_k(-dist) ordering.
  if (tid < NCHUNKS*KSEL) {
    float dm = pd[tid]; int im = pi[tid];
    int rank = 0;
    for (int j = 0; j < NCHUNKS*KSEL; ++j) {
      float dj = pd[j]; int ij = pi[j];
      rank += (dj < dm) || (dj == dm && ij < im);
    }
    if (rank < KSEL) { md[rank] = dm; mi[rank] = im; }
  }
  __syncthreads();
  if (tid == 0) {
    qn[0] = fmaxf(sqrtf(red0[0]+red0[1]+red0[2]+red0[3]), CEPS);
    qn[1] = fmaxf(sqrtf(red1[0]+red1[1]+red1[2]+red1[3]), CEPS);
  }
  __syncthreads();

  // 8 lanes per neighbor: fused gather + dot + norm for both tables
  const int g = tid >> 3;
  const int l = tid & 7;
  const int ix = mi[g];
  const float4* r0  = (const float4*)(C0 + (size_t)ix * D);
  const float4* r1  = (const float4*)(C1 + (size_t)ix * D);
  const float4* q04 = (const float4*)q0s;
  const float4* q14 = (const float4*)q1s;
  float dot0 = 0.f, nn0 = 0.f, dot1 = 0.f, nn1 = 0.f;
  #pragma unroll
  for (int r = 0; r < 16; ++r) {
    int e4 = r*8 + l;
    float4 v0 = r0[e4], qv0 = q04[e4];
    dot0 = fmaf(v0.x, qv0.x, fmaf(v0.y, qv0.y, fmaf(v0.z, qv0.z, fmaf(v0.w, qv0.w, dot0))));
    nn0  = fmaf(v0.x, v0.x,  fmaf(v0.y, v0.y,  fmaf(v0.z, v0.z,  fmaf(v0.w, v0.w,  nn0))));
    float4 v1 = r1[e4], qv1 = q14[e4];
    dot1 = fmaf(v1.x, qv1.x, fmaf(v1.y, qv1.y, fmaf(v1.z, qv1.z, fmaf(v1.w, qv1.w, dot1))));
    nn1  = fmaf(v1.x, v1.x,  fmaf(v1.y, v1.y,  fmaf(v1.z, v1.z,  fmaf(v1.w, v1.w,  nn1))));
  }
  #pragma unroll
  for (int o = 4; o > 0; o >>= 1) {
    dot0 += __shfl_xor(dot0, o, 64); nn0 += __shfl_xor(nn0, o, 64);
    dot1 += __shfl_xor(dot1, o, 64); nn1 += __shfl_xor(nn1, o, 64);
  }
  if (l == 0) {
    float c0 = dot0 / (fmaxf(sqrtf(nn0), CEPS) * qn[0]);
    float c1 = dot1 / (fmaxf(sqrtf(nn1), CEPS) * qn[1]);
    float cv = (c0 > c1) ? c0 : c1;
    out[(size_t)q * KSEL + g] = cv;
    cosj[g] = cv;
  }
  __syncthreads();
  if (tid == 0) {
    float s = 0.f;
    #pragma unroll
    for (int j = 0; j < KSEL; ++j) s += cosj[j];
    out[(size_t)n1 * KSEL + q] = s * (1.f / KSEL);
  }
}

// ---------------- launch ----------------
extern "C" void kernel_launch(void* const* d_in, const int* in_sizes, int n_in,
                              void* d_out, int out_size, void* d_ws, size_t ws_size,
                              hipStream_t stream)
{
  const float* Q0 = (const float*)d_in[0];
  const float* Q1 = (const float*)d_in[1];
  const float* C0 = (const float*)d_in[2];
  const float* C1 = (const float*)d_in[3];
  const int n1 = in_sizes[0] / D;   // 2048
  const int n2 = in_sizes[2] / D;   // 50000
  float* out = (float*)d_out;
  if (n1 <= 0 || n2 <= 0) return;

  float* wsf = (float*)d_ws;
  size_t c2n = ((size_t)n2 + 127) & ~(size_t)127;
  size_t q2n = ((size_t)n1 + 127) & ~(size_t)127;
  float* c2  = wsf;
  float* q2  = wsf + c2n;
  float* tkd = wsf + c2n + q2n;
  int*   tki = (int*)(wsf + c2n + q2n + (size_t)n1 * NCHUNKS * KSEL);
  // total ws: (c2n + q2n + 2*n1*NCHUNKS*KSEL)*4 ~ 2.3 MB

  rows_sumsq_kernel<<<(n2 + n1 + 3) / 4, 256, 0, stream>>>(C0, Q0, c2, q2, n2, n1);

  const int chunk = (n2 + NCHUNKS - 1) / NCHUNKS;
  const size_t smem1 = (size_t)MT*D*4 + (size_t)NT*KC*4 + (size_t)MT*(NT+1)*4
                     + (size_t)MT*33*4 * 2 + (size_t)MT*4;   // 139776 B
  (void)hipFuncSetAttribute((const void*)knn_phase1_kernel,
                            hipFuncAttributeMaxDynamicSharedMemorySize, (int)smem1);
  knn_phase1_kernel<<<dim3((n1 + MT - 1) / MT, NCHUNKS), NTH, smem1, stream>>>(
      Q0, C0, q2, c2, tkd, tki, n1, n2, chunk);

  knn_phase2_kernel<<<n1, 256, 0, stream>>>(Q0, Q1, C0, C1, tkd, tki, out, n1);
}

// Round 3
// 2977.333 us; speedup vs baseline: 2.1916x; 2.1916x over previous
//
#include <hip/hip_runtime.h>
#include <math.h>

// Brute-force KNN (L2, top-32) + cosine re-rank for MI355X.
// Phase 0: row sum-of-squares for cand_emb0 / query_emb0.
// Phase 1: fused distance-GEMM + per-chunk top-32.
//          16 queries x 256 cands per block, KC=16, 64KB LDS -> 2 blocks/CU.
//          Top-32 as unsorted register set (lanes 0..31) with replace-worst
//          (lexicographic (dist,idx) max-reduce); rank-sorted once at the end.
// Phase 2: exact merge (rank-select over 128) + gather + cosine/max/mean.

#define D      512
#define MT     16     // queries per WG (phase 1)
#define NT     256    // candidates per tile step
#define KC     16     // K chunk
#define TM     8      // queries per thread
#define TN     2      // candidates per thread ({tn, tn+128})
#define NTH    256    // threads per block
#define KSEL   32     // k
#define NCHUNKS 4
#define CEPS   1e-8f
#define INF    __builtin_inff()

// ---------------- Phase 0: row sum-of-squares ----------------
__global__ __launch_bounds__(256) void rows_sumsq_kernel(
    const float* __restrict__ C, const float* __restrict__ Q,
    float* __restrict__ c2, float* __restrict__ q2, int n2, int n1)
{
  int wid  = threadIdx.x >> 6;
  int lane = threadIdx.x & 63;
  int row  = blockIdx.x * 4 + wid;
  const float* src;
  float* dst;
  if (row < n2) { src = C + (size_t)row * D; dst = c2 + row; }
  else {
    int r = row - n2;
    if (r >= n1) return;
    src = Q + (size_t)r * D; dst = q2 + r;
  }
  const float4* s4 = (const float4*)src;
  float4 a = s4[lane];
  float4 b = s4[lane + 64];
  float s = a.x*a.x + a.y*a.y + a.z*a.z + a.w*a.w
          + b.x*b.x + b.y*b.y + b.z*b.z + b.w*b.w;
  #pragma unroll
  for (int o = 32; o > 0; o >>= 1) s += __shfl_down(s, o, 64);
  if (lane == 0) *dst = s;
}

// lexicographic max of (d,i) over lanes 0..31, broadcast to all 64 lanes
__device__ inline void worst_reduce(float dIn, int iIn, float& wd, int& wi) {
  float dd = dIn; int ii = iIn;
  #pragma unroll
  for (int o = 1; o <= 16; o <<= 1) {
    float dp = __shfl_xor(dd, o, 64);
    int   ip = __shfl_xor(ii, o, 64);
    bool take = (dp > dd) || (dp == dd && ip > ii);
    dd = take ? dp : dd;
    ii = take ? ip : ii;
  }
  wd = __shfl(dd, 0, 64);
  wi = __shfl(ii, 0, 64);
}

// ---------------- Phase 1: distance GEMM + partial top-k ----------------
// LDS: qs [16][512] 32KB | cs [256][16] swizzled 16KB | dl [16][256] 16KB = 64KB
__global__ __launch_bounds__(NTH, 2) void knn_phase1_kernel(
    const float* __restrict__ Q, const float* __restrict__ C,
    const float* __restrict__ q2g, const float* __restrict__ c2g,
    float* __restrict__ tkd, int* __restrict__ tki,
    int n1, int n2, int chunk)
{
  extern __shared__ char smem[];
  float* qs = (float*)smem;                 // [MT][D]
  float* cs = (float*)(smem + 32768);       // [NT][KC] quad-XOR swizzled
  float* dl = (float*)(smem + 49152);       // [MT][NT]

  const int tid = threadIdx.x;
  const int w   = tid >> 6;      // wave 0..3
  const int l   = tid & 63;      // lane
  const int tm  = tid >> 7;      // query group 0..1 (8 queries each)
  const int tn  = tid & 127;     // candidate lane: cands {tn, tn+128}
  const int mbase   = blockIdx.x * MT;
  const int chunkid = blockIdx.y;
  const int cbase0  = chunkid * chunk;
  const int cend    = min(cbase0 + chunk, n2);

  // stage queries (MT*D/4 = 2048 float4, 8 per thread)
  #pragma unroll
  for (int r = 0; r < 8; ++r) {
    int f  = tid + NTH * r;
    int m  = f >> 7;           // D/4 = 128 float4 per row
    int qd = f & 127;
    int gm = min(mbase + m, n1 - 1);
    ((float4*)qs)[f] = ((const float4*)(Q + (size_t)gm * D))[qd];
  }
  float q2v[TM];
  #pragma unroll
  for (int i = 0; i < TM; ++i) q2v[i] = q2g[min(mbase + tm*TM + i, n1 - 1)];

  // per-wave register top-32 sets: wave w owns queries w*4+t, entries in lanes 0..31
  float listd[4]; int listi[4];
  float wd4[4];   int wi4[4];     // cached worst (uniform across wave)
  #pragma unroll
  for (int t = 0; t < 4; ++t) {
    listd[t] = INF; listi[t] = 0x7fffffff;
    wd4[t]   = INF; wi4[t]   = 0x7fffffff;
  }

  float4 vr[4];
  auto LOADR = [&](int kc, int cb) {
    #pragma unroll
    for (int r = 0; r < 4; ++r) {
      int f  = tid + NTH * r;
      int n  = f >> 2;          // KC/4 = 4 quads per row
      int qd = f & 3;
      int gn = cb + n;
      float4 v = make_float4(0.f, 0.f, 0.f, 0.f);
      if (gn < cend) v = *((const float4*)(C + (size_t)gn * D + (size_t)kc * KC) + qd);
      vr[r] = v;
    }
  };
  auto STORE = [&]() {
    #pragma unroll
    for (int r = 0; r < 4; ++r) {
      int f  = tid + NTH * r;
      int n  = f >> 2;
      int qd = f & 3;
      int slot = qd ^ ((n >> 2) & 3);       // quad-XOR bank swizzle
      *((float4*)(cs + (size_t)n * KC) + slot) = vr[r];
    }
  };

  const int nsteps = (chunk + NT - 1) / NT;
  LOADR(0, cbase0);   // prologue prefetch

  for (int nt = 0; nt < nsteps; ++nt) {
    const int cbase = cbase0 + nt * NT;
    float acc[TM][TN]  = {};
    float acc2[TM][TN] = {};

    for (int kc = 0; kc < D/KC; ++kc) {
      __syncthreads();          // cs consumed by previous iter
      STORE();
      __syncthreads();
      if (kc + 1 < D/KC)        LOADR(kc + 1, cbase);
      else if (nt + 1 < nsteps) LOADR(0, cbase + NT);

      #pragma unroll
      for (int s = 0; s < KC/4; ++s) {
        float4 qf[TM];
        #pragma unroll
        for (int i = 0; i < TM; ++i)
          qf[i] = *((const float4*)(qs + (size_t)(tm*TM + i)*D + (size_t)kc*KC) + s);
        float4 cf[TN];
        #pragma unroll
        for (int j = 0; j < TN; ++j) {
          int row  = tn + 128*j;
          int slot = s ^ ((row >> 2) & 3);
          cf[j] = *((const float4*)(cs + (size_t)row * KC) + slot);
        }
        #pragma unroll
        for (int i = 0; i < TM; ++i)
          #pragma unroll
          for (int j = 0; j < TN; ++j) {
            float t = acc2[i][j];
            t = fmaf(qf[i].x, cf[j].x, t);
            t = fmaf(qf[i].y, cf[j].y, t);
            t = fmaf(qf[i].z, cf[j].z, t);
            t = fmaf(qf[i].w, cf[j].w, t);
            acc2[i][j] = t;
          }
      }
      if (kc & 1) {             // fold 32-element K-block (matches R1 numerics)
        #pragma unroll
        for (int i = 0; i < TM; ++i)
          #pragma unroll
          for (int j = 0; j < TN; ++j) { acc[i][j] += acc2[i][j]; acc2[i][j] = 0.f; }
      }
    }

    // distances -> dl  (lane-stride-1 writes: conflict-free)
    #pragma unroll
    for (int j = 0; j < TN; ++j) {
      int p  = tn + 128*j;
      int gn = cbase + p;
      bool valid = (gn < cend);
      float c2v = valid ? c2g[gn] : 0.f;
      #pragma unroll
      for (int i = 0; i < TM; ++i) {
        float d2 = q2v[i] + c2v - 2.f * acc[i][j];
        dl[(size_t)(tm*TM + i)*NT + p] = valid ? sqrtf(fmaxf(d2, 0.f)) : INF;
      }
    }
    __syncthreads();

    // wave-parallel filter + replace-worst (wave w owns queries w*4+t)
    #pragma unroll
    for (int t = 0; t < 4; ++t) {
      const int m = w*4 + t;
      #pragma unroll
      for (int jj = 0; jj < 4; ++jj) {
        float dv = dl[(size_t)m*NT + l + 64*jj];
        unsigned long long mask = __ballot(dv < wd4[t]);
        while (mask) {
          int L = __ffsll(mask) - 1;
          mask &= mask - 1;
          float dnew = dl[(size_t)m*NT + 64*jj + L];   // broadcast read
          int   ci   = cbase + 64*jj + L;
          // lexicographic accept vs current worst (uniform branch)
          if ((dnew < wd4[t]) || (dnew == wd4[t] && ci < wi4[t])) {
            bool isw = (l < 32) && (listd[t] == wd4[t]) && (listi[t] == wi4[t]);
            int  wl  = __ffsll(__ballot(isw)) - 1;
            if (l == wl) { listd[t] = dnew; listi[t] = ci; }
            worst_reduce((l < 32) ? listd[t] : -1.f,
                         (l < 32) ? listi[t] : -1, wd4[t], wi4[t]);
          }
        }
      }
    }
  }

  // rank-sort the 32 register entries once, write per-chunk sorted top-32
  #pragma unroll
  for (int t = 0; t < 4; ++t) {
    int gq = mbase + w*4 + t;
    float d = listd[t]; int i = listi[t];
    int rank = 0;
    #pragma unroll
    for (int j = 0; j < KSEL; ++j) {
      float dj = __shfl(listd[t], j, 64);
      int   ij = __shfl(listi[t], j, 64);
      rank += (dj < d) || (dj == d && ij < i);
    }
    if (l < 32 && gq < n1) {
      size_t o = ((size_t)gq * NCHUNKS + chunkid) * KSEL + rank;
      tkd[o] = d;
      tki[o] = i;
    }
  }
}

// ---------------- Phase 2: merge + gather + cosine ----------------
__global__ __launch_bounds__(256) void knn_phase2_kernel(
    const float* __restrict__ Q0, const float* __restrict__ Q1,
    const float* __restrict__ C0, const float* __restrict__ C1,
    const float* __restrict__ tkd, const int* __restrict__ tki,
    float* __restrict__ out, int n1)
{
  __shared__ float q0s[D], q1s[D];
  __shared__ float pd[NCHUNKS*KSEL];
  __shared__ int   pi[NCHUNKS*KSEL];
  __shared__ float md[KSEL];
  __shared__ int   mi[KSEL];
  __shared__ float cosj[KSEL];
  __shared__ float red0[4], red1[4];
  __shared__ float qn[2];

  const int q   = blockIdx.x;
  const int tid = threadIdx.x;

  if (tid < 128) {
    ((float4*)q0s)[tid] = ((const float4*)(Q0 + (size_t)q*D))[tid];
    pd[tid] = tkd[(size_t)q*NCHUNKS*KSEL + tid];
    pi[tid] = tki[(size_t)q*NCHUNKS*KSEL + tid];
  } else {
    ((float4*)q1s)[tid-128] = ((const float4*)(Q1 + (size_t)q*D))[tid-128];
  }
  __syncthreads();

  float a0 = q0s[tid], b0 = q0s[tid+256];
  float a1 = q1s[tid], b1 = q1s[tid+256];
  float s0 = a0*a0 + b0*b0;
  float s1 = a1*a1 + b1*b1;
  #pragma unroll
  for (int o = 32; o > 0; o >>= 1) { s0 += __shfl_down(s0, o, 64); s1 += __shfl_down(s1, o, 64); }
  int lane = tid & 63, wid = tid >> 6;
  if (lane == 0) { red0[wid] = s0; red1[wid] = s1; }

  // exact top-32 of 128 partials via rank selection, (dist asc, idx asc)
  if (tid < NCHUNKS*KSEL) {
    float dm = pd[tid]; int im = pi[tid];
    int rank = 0;
    for (int j = 0; j < NCHUNKS*KSEL; ++j) {
      float dj = pd[j]; int ij = pi[j];
      rank += (dj < dm) || (dj == dm && ij < im);
    }
    if (rank < KSEL) { md[rank] = dm; mi[rank] = im; }
  }
  __syncthreads();
  if (tid == 0) {
    qn[0] = fmaxf(sqrtf(red0[0]+red0[1]+red0[2]+red0[3]), CEPS);
    qn[1] = fmaxf(sqrtf(red1[0]+red1[1]+red1[2]+red1[3]), CEPS);
  }
  __syncthreads();

  // 8 lanes per neighbor: fused gather + dot + norm for both tables
  const int g = tid >> 3;
  const int ll = tid & 7;
  const int ix = mi[g];
  const float4* r0  = (const float4*)(C0 + (size_t)ix * D);
  const float4* r1  = (const float4*)(C1 + (size_t)ix * D);
  const float4* q04 = (const float4*)q0s;
  const float4* q14 = (const float4*)q1s;
  float dot0 = 0.f, nn0 = 0.f, dot1 = 0.f, nn1 = 0.f;
  #pragma unroll
  for (int r = 0; r < 16; ++r) {
    int e4 = r*8 + ll;
    float4 v0 = r0[e4], qv0 = q04[e4];
    dot0 = fmaf(v0.x, qv0.x, fmaf(v0.y, qv0.y, fmaf(v0.z, qv0.z, fmaf(v0.w, qv0.w, dot0))));
    nn0  = fmaf(v0.x, v0.x,  fmaf(v0.y, v0.y,  fmaf(v0.z, v0.z,  fmaf(v0.w, v0.w,  nn0))));
    float4 v1 = r1[e4], qv1 = q14[e4];
    dot1 = fmaf(v1.x, qv1.x, fmaf(v1.y, qv1.y, fmaf(v1.z, qv1.z, fmaf(v1.w, qv1.w, dot1))));
    nn1  = fmaf(v1.x, v1.x,  fmaf(v1.y, v1.y,  fmaf(v1.z, v1.z,  fmaf(v1.w, v1.w,  nn1))));
  }
  #pragma unroll
  for (int o = 4; o > 0; o >>= 1) {
    dot0 += __shfl_xor(dot0, o, 64); nn0 += __shfl_xor(nn0, o, 64);
    dot1 += __shfl_xor(dot1, o, 64); nn1 += __shfl_xor(nn1, o, 64);
  }
  if (ll == 0) {
    float c0 = dot0 / (fmaxf(sqrtf(nn0), CEPS) * qn[0]);
    float c1 = dot1 / (fmaxf(sqrtf(nn1), CEPS) * qn[1]);
    float cv = (c0 > c1) ? c0 : c1;
    out[(size_t)q * KSEL + g] = cv;
    cosj[g] = cv;
  }
  __syncthreads();
  if (tid == 0) {
    float s = 0.f;
    #pragma unroll
    for (int j = 0; j < KSEL; ++j) s += cosj[j];
    out[(size_t)n1 * KSEL + q] = s * (1.f / KSEL);
  }
}

// ---------------- launch ----------------
extern "C" void kernel_launch(void* const* d_in, const int* in_sizes, int n_in,
                              void* d_out, int out_size, void* d_ws, size_t ws_size,
                              hipStream_t stream)
{
  const float* Q0 = (const float*)d_in[0];
  const float* Q1 = (const float*)d_in[1];
  const float* C0 = (const float*)d_in[2];
  const float* C1 = (const float*)d_in[3];
  const int n1 = in_sizes[0] / D;   // 2048
  const int n2 = in_sizes[2] / D;   // 50000
  float* out = (float*)d_out;
  if (n1 <= 0 || n2 <= 0) return;

  float* wsf = (float*)d_ws;
  size_t c2n = ((size_t)n2 + 127) & ~(size_t)127;
  size_t q2n = ((size_t)n1 + 127) & ~(size_t)127;
  float* c2  = wsf;
  float* q2  = wsf + c2n;
  float* tkd = wsf + c2n + q2n;
  int*   tki = (int*)(wsf + c2n + q2n + (size_t)n1 * NCHUNKS * KSEL);

  rows_sumsq_kernel<<<(n2 + n1 + 3) / 4, 256, 0, stream>>>(C0, Q0, c2, q2, n2, n1);

  const int chunk = (n2 + NCHUNKS - 1) / NCHUNKS;
  const size_t smem1 = 65536;   // qs 32KB + cs 16KB + dl 16KB
  (void)hipFuncSetAttribute((const void*)knn_phase1_kernel,
                            hipFuncAttributeMaxDynamicSharedMemorySize, (int)smem1);
  knn_phase1_kernel<<<dim3((n1 + MT - 1) / MT, NCHUNKS), NTH, smem1, stream>>>(
      Q0, C0, q2, c2, tkd, tki, n1, n2, chunk);

  knn_phase2_kernel<<<n1, 256, 0, stream>>>(Q0, Q1, C0, C1, tkd, tki, out, n1);
}

// Round 4
// 2215.747 us; speedup vs baseline: 2.9448x; 1.3437x over previous
//
#include <hip/hip_runtime.h>
#include <math.h>

// KNN (L2 top-32) + cosine re-rank, MI355X.
// P0: row sum-of-squares.
// P1: bf16-split 3-pass MFMA distance GEMM (32x32x16), per-chunk noisy top-32.
//     64q x 512c tiles, KC=64, 8 waves, 160KB LDS, reg-prefetch pipeline.
// P2: merge 8x32 -> noisy top-48 -> EXACT fp32 rescore -> exact top-32 -> cosine.

#define D       512
#define MT      64
#define NT      512
#define KC      64
#define NTH     512
#define KSEL    32
#define NSELMX  48
#define CEPS    1e-8f
#define INF     __builtin_inff()

using s16x8  = __attribute__((ext_vector_type(8)))  short;
using f32x16 = __attribute__((ext_vector_type(16))) float;

// ---------------- Phase 0 ----------------
__global__ __launch_bounds__(256) void rows_sumsq_kernel(
    const float* __restrict__ C, const float* __restrict__ Q,
    float* __restrict__ c2, float* __restrict__ q2, int n2, int n1)
{
  int wid  = threadIdx.x >> 6;
  int lane = threadIdx.x & 63;
  int row  = blockIdx.x * 4 + wid;
  const float* src; float* dst;
  if (row < n2) { src = C + (size_t)row * D; dst = c2 + row; }
  else { int r = row - n2; if (r >= n1) return; src = Q + (size_t)r * D; dst = q2 + r; }
  const float4* s4 = (const float4*)src;
  float4 a = s4[lane], b = s4[lane + 64];
  float s = a.x*a.x + a.y*a.y + a.z*a.z + a.w*a.w
          + b.x*b.x + b.y*b.y + b.z*b.z + b.w*b.w;
  #pragma unroll
  for (int o = 32; o > 0; o >>= 1) s += __shfl_down(s, o, 64);
  if (lane == 0) *dst = s;
}

// lexicographic max of (d,i) over lanes 0..31, broadcast to all lanes
__device__ inline void worst_reduce(float dIn, int iIn, float& wd, int& wi) {
  float dd = dIn; int ii = iIn;
  #pragma unroll
  for (int o = 1; o <= 16; o <<= 1) {
    float dp = __shfl_xor(dd, o, 64);
    int   ip = __shfl_xor(ii, o, 64);
    bool take = (dp > dd) || (dp == dd && ip > ii);
    dd = take ? dp : dd; ii = take ? ip : ii;
  }
  wd = __shfl(dd, 0, 64); wi = __shfl(ii, 0, 64);
}

// fp32 -> (bf16_hi, bf16_lo) RTN split, 8 elements, packed for ds_write_b128
__device__ inline void cvt8(const float4 a, const float4 b, int4& hi, int4& lo) {
  float x[8] = {a.x, a.y, a.z, a.w, b.x, b.y, b.z, b.w};
  unsigned int hw[8], lw[8];
  #pragma unroll
  for (int j = 0; j < 8; ++j) {
    unsigned int ux = __float_as_uint(x[j]);
    unsigned int rh = (ux + 0x7fffu + ((ux >> 16) & 1u)) & 0xffff0000u;
    float rl = x[j] - __uint_as_float(rh);
    unsigned int ul = __float_as_uint(rl);
    hw[j] = rh >> 16;
    lw[j] = (ul + 0x7fffu + ((ul >> 16) & 1u)) >> 16;
  }
  hi = make_int4((int)(hw[0]|(hw[1]<<16)), (int)(hw[2]|(hw[3]<<16)),
                 (int)(hw[4]|(hw[5]<<16)), (int)(hw[6]|(hw[7]<<16)));
  lo = make_int4((int)(lw[0]|(lw[1]<<16)), (int)(lw[2]|(lw[3]<<16)),
                 (int)(lw[4]|(lw[5]<<16)), (int)(lw[6]|(lw[7]<<16)));
}

// ---------------- Phase 1 ----------------
// LDS: qh[64][64]u16 8K | ql 8K | ch[512][64]u16 64K | cl 64K | dl[8][512]f32 16K = 160K
__global__ __launch_bounds__(NTH) void knn_phase1_kernel(
    const float* __restrict__ Q, const float* __restrict__ C,
    const float* __restrict__ q2g, const float* __restrict__ c2g,
    float* __restrict__ tkd, int* __restrict__ tki,
    int n1, int n2, int chunk, int nc)
{
  extern __shared__ char smem[];
  unsigned short* qh = (unsigned short*)smem;      // [64][64]
  unsigned short* ql = qh + 64*64;
  unsigned short* ch = ql + 64*64;                 // [512][64]
  unsigned short* cl = ch + 512*64;
  float* dl = (float*)(smem + 147456);             // [8][512]

  const int tid  = threadIdx.x;
  const int w    = tid >> 6;
  const int l    = tid & 63;
  const int l31  = l & 31;
  const int half = l >> 5;
  const int mbase   = blockIdx.x * MT;
  const int chunkid = blockIdx.y;
  const int cbase0  = chunkid * chunk;
  const int cend    = min(cbase0 + chunk, n2);

  // per-wave q2 for owned rows (row ≡ w mod 8)
  float q2w[8];
  #pragma unroll
  for (int g = 0; g < 8; ++g) q2w[g] = q2g[min(mbase + g*8 + w, n1 - 1)];

  // 8 lists per wave (list g = row mbase+g*8+w), entries in lanes 0..31
  float listd[8]; int listi[8]; float wd4[8]; int wi4[8];
  #pragma unroll
  for (int g = 0; g < 8; ++g) { listd[g]=INF; listi[g]=0x7fffffff; wd4[g]=INF; wi4[g]=0x7fffffff; }

  const int srow = tid >> 3;        // staging row-within-64
  const int sk8  = (tid & 7) * 8;   // staging k-offset
  const int su   = (tid & 7);       // staging unit

  float4 cva[8][2], qva[2];
  auto LOADR = [&](int kb, int cb) {
    {
      int gr = min(mbase + srow, n1 - 1);
      const float4* p = (const float4*)(Q + (size_t)gr * D + kb*KC + sk8);
      qva[0] = p[0]; qva[1] = p[1];
    }
    #pragma unroll
    for (int r = 0; r < 8; ++r) {
      int gn = cb + srow + 64*r;
      if (gn < cend) {
        const float4* p = (const float4*)(C + (size_t)gn * D + kb*KC + sk8);
        cva[r][0] = p[0]; cva[r][1] = p[1];
      } else {
        cva[r][0] = make_float4(0.f,0.f,0.f,0.f);
        cva[r][1] = make_float4(0.f,0.f,0.f,0.f);
      }
    }
  };
  auto STORE = [&]() {
    int4 hi, lo;
    {
      int idx = srow*64 + (su ^ (srow & 7))*8;
      cvt8(qva[0], qva[1], hi, lo);
      *(int4*)(qh + idx) = hi; *(int4*)(ql + idx) = lo;
    }
    #pragma unroll
    for (int r = 0; r < 8; ++r) {
      int row = srow + 64*r;
      int idx = row*64 + (su ^ (row & 7))*8;
      cvt8(cva[r][0], cva[r][1], hi, lo);
      *(int4*)(ch + idx) = hi; *(int4*)(cl + idx) = lo;
    }
  };

  f32x16 zf;
  #pragma unroll
  for (int e = 0; e < 16; ++e) zf[e] = 0.f;

  const int nsteps = (cend - cbase0 + NT - 1) / NT;
  LOADR(0, cbase0);

  for (int nt = 0; nt < nsteps; ++nt) {
    const int cbase = cbase0 + nt * NT;
    f32x16 acc[2][2];
    #pragma unroll
    for (int rt = 0; rt < 2; ++rt)
      #pragma unroll
      for (int ct = 0; ct < 2; ++ct) acc[rt][ct] = zf;

    for (int kb = 0; kb < D/KC; ++kb) {
      __syncthreads();
      STORE();
      __syncthreads();
      if (kb + 1 < D/KC)        LOADR(kb + 1, cbase);
      else if (nt + 1 < nsteps) LOADR(0, cbase + NT);

      #pragma unroll
      for (int ks = 0; ks < 4; ++ks) {
        const int u = 2*ks + half;
        s16x8 qf[2][2], cf[2][2];
        #pragma unroll
        for (int rt = 0; rt < 2; ++rt) {
          int r = rt*32 + l31;
          int idx = r*64 + (u ^ (r & 7))*8;
          qf[rt][0] = *(const s16x8*)(qh + idx);
          qf[rt][1] = *(const s16x8*)(ql + idx);
        }
        #pragma unroll
        for (int ct = 0; ct < 2; ++ct) {
          int c = w*64 + ct*32 + l31;
          int idx = c*64 + (u ^ (c & 7))*8;
          cf[ct][0] = *(const s16x8*)(ch + idx);
          cf[ct][1] = *(const s16x8*)(cl + idx);
        }
        #pragma unroll
        for (int rt = 0; rt < 2; ++rt)
          #pragma unroll
          for (int ct = 0; ct < 2; ++ct) {
            acc[rt][ct] = __builtin_amdgcn_mfma_f32_32x32x16_bf16(qf[rt][0], cf[ct][0], acc[rt][ct], 0, 0, 0);
            acc[rt][ct] = __builtin_amdgcn_mfma_f32_32x32x16_bf16(qf[rt][0], cf[ct][1], acc[rt][ct], 0, 0, 0);
            acc[rt][ct] = __builtin_amdgcn_mfma_f32_32x32x16_bf16(qf[rt][1], cf[ct][0], acc[rt][ct], 0, 0, 0);
          }
      }
    }

    // epilogue: s = c2 - 2*dot -> dl (8-row groups); filter with exact-form dist
    float c2v[2]; int vld[2];
    #pragma unroll
    for (int ct = 0; ct < 2; ++ct) {
      int gc = cbase + w*64 + ct*32 + l31;
      vld[ct] = (gc < cend);
      c2v[ct] = vld[ct] ? c2g[gc] : 0.f;
    }

    #pragma unroll
    for (int g = 0; g < 8; ++g) {
      const int rt = g >> 2, qq = g & 3;
      #pragma unroll
      for (int jj = 0; jj < 4; ++jj)
        #pragma unroll
        for (int ct = 0; ct < 2; ++ct) {
          float a = acc[rt][ct][4*qq + jj];
          float s = c2v[ct] - 2.f * a;
          dl[(4*half + jj)*512 + w*64 + ct*32 + l31] = vld[ct] ? s : INF;
        }
      __syncthreads();
      // wave w filters row g*8+w of this group
      const float q2u = q2w[g];
      #pragma unroll
      for (int j2 = 0; j2 < 8; ++j2) {
        float sv = dl[w*512 + l + 64*j2];
        float dv = sqrtf(fmaxf(q2u + sv, 0.f));           // INF stays INF
        unsigned long long mask = __ballot(dv < wd4[g]);
        while (mask) {
          int L = __ffsll(mask) - 1; mask &= mask - 1;
          float dnew = __shfl(dv, L, 64);
          int ci = cbase + 64*j2 + L;
          if ((dnew < wd4[g]) || (dnew == wd4[g] && ci < wi4[g])) {
            bool isw = (l < 32) && (listd[g] == wd4[g]) && (listi[g] == wi4[g]);
            int wl = __ffsll(__ballot(isw)) - 1;
            if (l == wl) { listd[g] = dnew; listi[g] = ci; }
            worst_reduce((l < 32) ? listd[g] : -1.f,
                         (l < 32) ? listi[g] : -1, wd4[g], wi4[g]);
          }
        }
      }
      __syncthreads();
    }
  }

  // rank-sort each list, write per-chunk top-32
  #pragma unroll
  for (int g = 0; g < 8; ++g) {
    int gq = mbase + g*8 + w;
    float d = listd[g]; int i = listi[g];
    int rank = 0;
    #pragma unroll
    for (int j = 0; j < KSEL; ++j) {
      float dj = __shfl(listd[g], j, 64);
      int   ij = __shfl(listi[g], j, 64);
      rank += (dj < d) || (dj == d && ij < i);
    }
    if (l < 32 && gq < n1) {
      size_t o = ((size_t)gq * nc + chunkid) * KSEL + rank;
      tkd[o] = d; tki[o] = i;
    }
  }
}

// ---------------- Phase 2: merge + exact rescore + cosine ----------------
__global__ __launch_bounds__(256) void knn_phase2_kernel(
    const float* __restrict__ Q0, const float* __restrict__ Q1,
    const float* __restrict__ C0, const float* __restrict__ C1,
    const float* __restrict__ q2g, const float* __restrict__ c2g,
    const float* __restrict__ tkd, const int* __restrict__ tki,
    float* __restrict__ out, int n1, int n2, int nc)
{
  __shared__ float q0s[D], q1s[D];
  __shared__ float pd[256]; __shared__ int pi[256];
  __shared__ float nd[NSELMX]; __shared__ int ni[NSELMX];
  __shared__ float de[NSELMX];
  __shared__ int   fi[KSEL];
  __shared__ float cosj[KSEL];
  __shared__ float red0[4], red1[4], qn[2];

  const int q = blockIdx.x, tid = threadIdx.x;
  const int npool = nc * KSEL;
  const int nsel  = (NSELMX < npool) ? NSELMX : npool;

  if (tid < 128) ((float4*)q0s)[tid] = ((const float4*)(Q0 + (size_t)q*D))[tid];
  else           ((float4*)q1s)[tid-128] = ((const float4*)(Q1 + (size_t)q*D))[tid-128];
  if (tid < npool) { pd[tid] = tkd[(size_t)q*npool + tid]; pi[tid] = tki[(size_t)q*npool + tid]; }
  __syncthreads();

  // query norms
  float a0 = q0s[tid], b0 = q0s[tid+256], a1 = q1s[tid], b1 = q1s[tid+256];
  float s0 = a0*a0 + b0*b0, s1 = a1*a1 + b1*b1;
  #pragma unroll
  for (int o = 32; o > 0; o >>= 1) { s0 += __shfl_down(s0, o, 64); s1 += __shfl_down(s1, o, 64); }
  int lane = tid & 63, wid = tid >> 6;
  if (lane == 0) { red0[wid] = s0; red1[wid] = s1; }

  // noisy top-nsel of the pool
  if (tid < npool) {
    float dm = pd[tid]; int im = pi[tid]; int rank = 0;
    for (int j = 0; j < npool; ++j) {
      float dj = pd[j]; int ij = pi[j];
      rank += (dj < dm) || (dj == dm && ij < im);
    }
    if (rank < nsel) { nd[rank] = dm; ni[rank] = im; }
  }
  __syncthreads();
  if (tid == 0) {
    qn[0] = fmaxf(sqrtf(red0[0]+red0[1]+red0[2]+red0[3]), CEPS);
    qn[1] = fmaxf(sqrtf(red1[0]+red1[1]+red1[2]+red1[3]), CEPS);
  }

  // exact fp32 rescore of the nsel survivors (8 lanes per cand)
  const float q2q = q2g[q];
  const int ll = tid & 7;
  for (int base = 0; base < NSELMX; base += 32) {
    int g = base + (tid >> 3);
    if (g < nsel) {
      int ix = ni[g];
      bool okx = (ix >= 0 && ix < n2);
      int ixc = okx ? ix : 0;
      const float4* r0  = (const float4*)(C0 + (size_t)ixc * D);
      const float4* q04 = (const float4*)q0s;
      float dot = 0.f;
      #pragma unroll
      for (int r = 0; r < 16; ++r) {
        float4 v = r0[r*8 + ll], u = q04[r*8 + ll];
        dot = fmaf(v.x,u.x, fmaf(v.y,u.y, fmaf(v.z,u.z, fmaf(v.w,u.w, dot))));
      }
      #pragma unroll
      for (int o = 4; o > 0; o >>= 1) dot += __shfl_xor(dot, o, 64);
      if (ll == 0) de[g] = okx ? sqrtf(fmaxf(q2q + c2g[ixc] - 2.f*dot, 0.f)) : INF;
    }
  }
  __syncthreads();

  // exact top-32 among nsel
  if (tid < nsel) {
    float dm = de[tid]; int im = ni[tid]; int rank = 0;
    for (int j = 0; j < nsel; ++j) {
      float dj = de[j]; int ij = ni[j];
      rank += (dj < dm) || (dj == dm && ij < im);
    }
    if (rank < KSEL) fi[rank] = im;
  }
  __syncthreads();

  // gather + cosine for the final 32
  const int g = tid >> 3;
  int ix = fi[g];
  ix = (ix >= 0 && ix < n2) ? ix : 0;
  const float4* r0  = (const float4*)(C0 + (size_t)ix * D);
  const float4* r1  = (const float4*)(C1 + (size_t)ix * D);
  const float4* q04 = (const float4*)q0s;
  const float4* q14 = (const float4*)q1s;
  float dot0 = 0.f, nn0 = 0.f, dot1 = 0.f, nn1 = 0.f;
  #pragma unroll
  for (int r = 0; r < 16; ++r) {
    int e4 = r*8 + ll;
    float4 v0 = r0[e4], qv0 = q04[e4];
    dot0 = fmaf(v0.x,qv0.x, fmaf(v0.y,qv0.y, fmaf(v0.z,qv0.z, fmaf(v0.w,qv0.w, dot0))));
    nn0  = fmaf(v0.x,v0.x,  fmaf(v0.y,v0.y,  fmaf(v0.z,v0.z,  fmaf(v0.w,v0.w,  nn0))));
    float4 v1 = r1[e4], qv1 = q14[e4];
    dot1 = fmaf(v1.x,qv1.x, fmaf(v1.y,qv1.y, fmaf(v1.z,qv1.z, fmaf(v1.w,qv1.w, dot1))));
    nn1  = fmaf(v1.x,v1.x,  fmaf(v1.y,v1.y,  fmaf(v1.z,v1.z,  fmaf(v1.w,v1.w,  nn1))));
  }
  #pragma unroll
  for (int o = 4; o > 0; o >>= 1) {
    dot0 += __shfl_xor(dot0, o, 64); nn0 += __shfl_xor(nn0, o, 64);
    dot1 += __shfl_xor(dot1, o, 64); nn1 += __shfl_xor(nn1, o, 64);
  }
  if (ll == 0) {
    float c0 = dot0 / (fmaxf(sqrtf(nn0), CEPS) * qn[0]);
    float c1 = dot1 / (fmaxf(sqrtf(nn1), CEPS) * qn[1]);
    float cv = (c0 > c1) ? c0 : c1;
    out[(size_t)q * KSEL + g] = cv;
    cosj[g] = cv;
  }
  __syncthreads();
  if (tid == 0) {
    float s = 0.f;
    #pragma unroll
    for (int j = 0; j < KSEL; ++j) s += cosj[j];
    out[(size_t)n1 * KSEL + q] = s * (1.f / KSEL);
  }
}

// ---------------- launch ----------------
extern "C" void kernel_launch(void* const* d_in, const int* in_sizes, int n_in,
                              void* d_out, int out_size, void* d_ws, size_t ws_size,
                              hipStream_t stream)
{
  const float* Q0 = (const float*)d_in[0];
  const float* Q1 = (const float*)d_in[1];
  const float* C0 = (const float*)d_in[2];
  const float* C1 = (const float*)d_in[3];
  const int n1 = in_sizes[0] / D;   // 2048
  const int n2 = in_sizes[2] / D;   // 50000
  float* out = (float*)d_out;
  if (n1 <= 0 || n2 <= 0) return;

  float* wsf = (float*)d_ws;
  size_t c2n = ((size_t)n2 + 127) & ~(size_t)127;
  size_t q2n = ((size_t)n1 + 127) & ~(size_t)127;

  int nc = 8;
  while (nc > 1 && (c2n + q2n + (size_t)n1 * nc * KSEL * 2) * 4 > ws_size) nc >>= 1;

  float* c2  = wsf;
  float* q2  = wsf + c2n;
  float* tkd = wsf + c2n + q2n;
  int*   tki = (int*)(wsf + c2n + q2n + (size_t)n1 * nc * KSEL);

  rows_sumsq_kernel<<<(n2 + n1 + 3) / 4, 256, 0, stream>>>(C0, Q0, c2, q2, n2, n1);

  const int chunk  = (n2 + nc - 1) / nc;
  const int mtiles = (n1 + MT - 1) / MT;
  const size_t smem1 = 163840;   // qh 8K + ql 8K + ch 64K + cl 64K + dl 16K
  (void)hipFuncSetAttribute((const void*)knn_phase1_kernel,
                            hipFuncAttributeMaxDynamicSharedMemorySize, (int)smem1);
  knn_phase1_kernel<<<dim3(mtiles, nc), NTH, smem1, stream>>>(
      Q0, C0, q2, c2, tkd, tki, n1, n2, chunk, nc);

  knn_phase2_kernel<<<n1, 256, 0, stream>>>(Q0, Q1, C0, C1, q2, c2, tkd, tki, out, n1, n2, nc);
}

// Round 5
// 1447.665 us; speedup vs baseline: 4.5073x; 1.5306x over previous
//
#include <hip/hip_runtime.h>
#include <math.h>

// KNN (L2 top-32) + cosine re-rank, MI355X.
// P-1: precvt — one-time fp32 -> bf16(hi, RTN) tables for C0/Q0 in ws.
// P0 : row sum-of-squares (exact fp32).
// P1 : 1-pass bf16 MFMA distance GEMM (32x32x16), 64q x 512c tiles, KC=64,
//      global_load_lds DMA staging (pre-swizzled source, linear LDS dest),
//      double-buffered 160KB LDS, counted vmcnt(9), per-chunk noisy top-32.
// P2 : merge 8x32 -> noisy top-64 -> EXACT fp32 rescore -> exact top-32 -> cosine.
// Fallback (small ws): R4's in-kernel-conversion 3-pass kernel (proven).

#define D       512
#define MT      64
#define NT      512
#define KC      64
#define NTH     512
#define KSEL    32
#define NSELMX  64
#define NCF     8      // chunks, fast path
#define CEPS    1e-8f
#define INF     __builtin_inff()

using s16x8  = __attribute__((ext_vector_type(8)))  short;
using f32x16 = __attribute__((ext_vector_type(16))) float;

__device__ __forceinline__ void async16(const void* g, void* s) {
  __builtin_amdgcn_global_load_lds(
      (const __attribute__((address_space(1))) unsigned int*)g,
      (__attribute__((address_space(3))) unsigned int*)s, 16, 0, 0);
}

// two fp32 -> packed bf16 pair (RTN)
__device__ __forceinline__ unsigned int bfhi2(float x0, float x1) {
  unsigned int u0 = __float_as_uint(x0), u1 = __float_as_uint(x1);
  u0 = (u0 + 0x7fffu + ((u0 >> 16) & 1u)) >> 16;
  u1 = (u1 + 0x7fffu + ((u1 >> 16) & 1u)) & 0xffff0000u;
  return u0 | u1;
}

// ---------------- P-1: one-time bf16 conversion ----------------
__global__ __launch_bounds__(256) void precvt_kernel(
    const float* __restrict__ C, const float* __restrict__ Q,
    unsigned short* __restrict__ Cb, unsigned short* __restrict__ Qb,
    int n2e8, int n1e8)
{
  int i = blockIdx.x * 256 + threadIdx.x;
  const float* src; unsigned short* dst;
  if (i < n2e8) { src = C + (size_t)i * 8; dst = Cb + (size_t)i * 8; }
  else if (i < n2e8 + n1e8) {
    int r = i - n2e8;
    src = Q + (size_t)r * 8; dst = Qb + (size_t)r * 8;
  } else return;
  float4 a = ((const float4*)src)[0], b = ((const float4*)src)[1];
  int4 h;
  h.x = (int)bfhi2(a.x, a.y); h.y = (int)bfhi2(a.z, a.w);
  h.z = (int)bfhi2(b.x, b.y); h.w = (int)bfhi2(b.z, b.w);
  *(int4*)dst = h;
}

// ---------------- Phase 0 ----------------
__global__ __launch_bounds__(256) void rows_sumsq_kernel(
    const float* __restrict__ C, const float* __restrict__ Q,
    float* __restrict__ c2, float* __restrict__ q2, int n2, int n1)
{
  int wid  = threadIdx.x >> 6;
  int lane = threadIdx.x & 63;
  int row  = blockIdx.x * 4 + wid;
  const float* src; float* dst;
  if (row < n2) { src = C + (size_t)row * D; dst = c2 + row; }
  else { int r = row - n2; if (r >= n1) return; src = Q + (size_t)r * D; dst = q2 + r; }
  const float4* s4 = (const float4*)src;
  float4 a = s4[lane], b = s4[lane + 64];
  float s = a.x*a.x + a.y*a.y + a.z*a.z + a.w*a.w
          + b.x*b.x + b.y*b.y + b.z*b.z + b.w*b.w;
  #pragma unroll
  for (int o = 32; o > 0; o >>= 1) s += __shfl_down(s, o, 64);
  if (lane == 0) *dst = s;
}

// lexicographic max of (d,i) over lanes 0..31, broadcast to all lanes
__device__ inline void worst_reduce(float dIn, int iIn, float& wd, int& wi) {
  float dd = dIn; int ii = iIn;
  #pragma unroll
  for (int o = 1; o <= 16; o <<= 1) {
    float dp = __shfl_xor(dd, o, 64);
    int   ip = __shfl_xor(ii, o, 64);
    bool take = (dp > dd) || (dp == dd && ip > ii);
    dd = take ? dp : dd; ii = take ? ip : ii;
  }
  wd = __shfl(dd, 0, 64); wi = __shfl(ii, 0, 64);
}

// fp32 -> (bf16_hi, bf16_lo) split (fallback kernel only)
__device__ inline void cvt8(const float4 a, const float4 b, int4& hi, int4& lo) {
  float x[8] = {a.x, a.y, a.z, a.w, b.x, b.y, b.z, b.w};
  unsigned int hw[8], lw[8];
  #pragma unroll
  for (int j = 0; j < 8; ++j) {
    unsigned int ux = __float_as_uint(x[j]);
    unsigned int rh = (ux + 0x7fffu + ((ux >> 16) & 1u)) & 0xffff0000u;
    float rl = x[j] - __uint_as_float(rh);
    unsigned int ul = __float_as_uint(rl);
    hw[j] = rh >> 16;
    lw[j] = (ul + 0x7fffu + ((ul >> 16) & 1u)) >> 16;
  }
  hi = make_int4((int)(hw[0]|(hw[1]<<16)), (int)(hw[2]|(hw[3]<<16)),
                 (int)(hw[4]|(hw[5]<<16)), (int)(hw[6]|(hw[7]<<16)));
  lo = make_int4((int)(lw[0]|(lw[1]<<16)), (int)(lw[2]|(lw[3]<<16)),
                 (int)(lw[4]|(lw[5]<<16)), (int)(lw[6]|(lw[7]<<16)));
}

// ---------------- Phase 1 (fast): DMA-staged 1-pass bf16 MFMA ----------------
// LDS: qh dbuf 2x8K | ch dbuf 2x64K | dl [8][512] 16K  = 160K
__global__ __launch_bounds__(NTH) void knn_phase1_bf_kernel(
    const unsigned short* __restrict__ Qb, const unsigned short* __restrict__ Cb,
    const float* __restrict__ q2g, const float* __restrict__ c2g,
    float* __restrict__ tkd, int* __restrict__ tki,
    int n1, int n2, int chunk, int nc)
{
  extern __shared__ char smem[];
  unsigned short* qh = (unsigned short*)smem;                // 2 x [64][64]
  unsigned short* ch = qh + 2*64*64;                         // 2 x [512][64]
  float* dl = (float*)(smem + 147456);                       // [8][512]

  const int tid  = threadIdx.x;
  const int w    = tid >> 6;
  const int l    = tid & 63;
  const int l31  = l & 31;
  const int half = l >> 5;
  const int mbase   = blockIdx.x * MT;
  const int chunkid = blockIdx.y;
  const int cbase0  = chunkid * chunk;
  const int cend    = min(cbase0 + chunk, n2);

  float q2w[8];
  #pragma unroll
  for (int g = 0; g < 8; ++g) q2w[g] = q2g[min(mbase + g*8 + w, n1 - 1)];

  float listd[8]; int listi[8]; float wd4[8]; int wi4[8];
  #pragma unroll
  for (int g = 0; g < 8; ++g) { listd[g]=INF; listi[g]=0x7fffffff; wd4[g]=INF; wi4[g]=0x7fffffff; }

  const int lrow = l >> 3;                 // row-within-8 of this lane
  const int su   = (l & 7) ^ lrow;         // pre-swizzled source unit

  // stage K-block kb of tile at cb into buffer buf (9 x global_load_lds / wave)
  auto STAGE = [&](int buf, int kb, int cb) {
    {
      int gm = min(mbase + w*8 + lrow, n1 - 1);
      const unsigned short* src = Qb + (size_t)gm * D + kb*KC + su*8;
      unsigned short* dst = qh + buf*(64*64) + (w*8)*64;     // wave-uniform base
      async16(src, dst);
    }
    #pragma unroll
    for (int i = 0; i < 8; ++i) {
      int gn = cb + w*64 + i*8 + lrow;                       // may overrun cend (padded)
      const unsigned short* src = Cb + (size_t)gn * D + kb*KC + su*8;
      unsigned short* dst = ch + buf*(512*64) + (w*64 + i*8)*64;
      async16(src, dst);
    }
  };

  f32x16 zf;
  #pragma unroll
  for (int e = 0; e < 16; ++e) zf[e] = 0.f;

  const int nsteps = (cend - cbase0 + NT - 1) / NT;
  int b = 0;
  STAGE(0, 0, cbase0);
  __syncthreads();            // drain prologue (vmcnt 0), clean counters

  for (int nt = 0; nt < nsteps; ++nt) {
    const int cbase = cbase0 + nt * NT;
    f32x16 acc[2][2];
    #pragma unroll
    for (int rt = 0; rt < 2; ++rt)
      #pragma unroll
      for (int ct = 0; ct < 2; ++ct) acc[rt][ct] = zf;

    for (int kb = 0; kb < D/KC; ++kb) {
      // issue next stage into b^1; wait current buffer b (counted, never 0)
      if (kb + 1 < D/KC) {
        STAGE(b^1, kb+1, cbase);
        asm volatile("s_waitcnt vmcnt(9)" ::: "memory");
      } else if (nt + 1 < nsteps) {
        STAGE(b^1, 0, cbase + NT);
        asm volatile("s_waitcnt vmcnt(9)" ::: "memory");
      } else {
        asm volatile("s_waitcnt vmcnt(0)" ::: "memory");
      }
      __builtin_amdgcn_s_barrier();
      __builtin_amdgcn_sched_barrier(0);

      const unsigned short* qb = qh + b*(64*64);
      const unsigned short* cbf = ch + b*(512*64);
      #pragma unroll
      for (int ks = 0; ks < 4; ++ks) {
        const int u = 2*ks + half;
        s16x8 qf[2], cf[2];
        #pragma unroll
        for (int rt = 0; rt < 2; ++rt) {
          int r = rt*32 + l31;
          qf[rt] = *(const s16x8*)(qb + r*64 + (u ^ (r & 7))*8);
        }
        #pragma unroll
        for (int ct = 0; ct < 2; ++ct) {
          int c = w*64 + ct*32 + l31;
          cf[ct] = *(const s16x8*)(cbf + c*64 + (u ^ (c & 7))*8);
        }
        #pragma unroll
        for (int rt = 0; rt < 2; ++rt)
          #pragma unroll
          for (int ct = 0; ct < 2; ++ct)
            acc[rt][ct] = __builtin_amdgcn_mfma_f32_32x32x16_bf16(qf[rt], cf[ct], acc[rt][ct], 0, 0, 0);
      }
      // all my LDS reads done, then block-wide rendezvous (keeps vmcnt in flight)
      asm volatile("s_waitcnt lgkmcnt(0)" ::: "memory");
      __builtin_amdgcn_s_barrier();
      __builtin_amdgcn_sched_barrier(0);
      b ^= 1;
    }

    // epilogue: s = c2 - 2*dot -> dl (8-row groups); filter
    float c2v[2]; int vld[2];
    #pragma unroll
    for (int ct = 0; ct < 2; ++ct) {
      int gc = cbase + w*64 + ct*32 + l31;
      vld[ct] = (gc < cend);
      c2v[ct] = vld[ct] ? c2g[gc] : 0.f;
    }
    #pragma unroll
    for (int g = 0; g < 8; ++g) {
      const int rt = g >> 2, qq = g & 3;
      #pragma unroll
      for (int jj = 0; jj < 4; ++jj)
        #pragma unroll
        for (int ct = 0; ct < 2; ++ct) {
          float a = acc[rt][ct][4*qq + jj];
          float s = c2v[ct] - 2.f * a;
          dl[(4*half + jj)*512 + w*64 + ct*32 + l31] = vld[ct] ? s : INF;
        }
      __syncthreads();
      const float q2u = q2w[g];
      #pragma unroll
      for (int j2 = 0; j2 < 8; ++j2) {
        float sv = dl[w*512 + l + 64*j2];
        float dv = sqrtf(fmaxf(q2u + sv, 0.f));
        unsigned long long mask = __ballot(dv < wd4[g]);
        while (mask) {
          int L = __ffsll(mask) - 1; mask &= mask - 1;
          float dnew = __shfl(dv, L, 64);
          int ci = cbase + 64*j2 + L;
          if ((dnew < wd4[g]) || (dnew == wd4[g] && ci < wi4[g])) {
            bool isw = (l < 32) && (listd[g] == wd4[g]) && (listi[g] == wi4[g]);
            int wl = __ffsll(__ballot(isw)) - 1;
            if (l == wl) { listd[g] = dnew; listi[g] = ci; }
            worst_reduce((l < 32) ? listd[g] : -1.f,
                         (l < 32) ? listi[g] : -1, wd4[g], wi4[g]);
          }
        }
      }
      __syncthreads();
    }
  }

  // rank-sort each list, write per-chunk top-32
  #pragma unroll
  for (int g = 0; g < 8; ++g) {
    int gq = mbase + g*8 + w;
    float d = listd[g]; int i = listi[g];
    int rank = 0;
    #pragma unroll
    for (int j = 0; j < KSEL; ++j) {
      float dj = __shfl(listd[g], j, 64);
      int   ij = __shfl(listi[g], j, 64);
      rank += (dj < d) || (dj == d && ij < i);
    }
    if (l < 32 && gq < n1) {
      size_t o = ((size_t)gq * nc + chunkid) * KSEL + rank;
      tkd[o] = d; tki[o] = i;
    }
  }
}

// ---------------- Phase 1 (fallback): R4 in-kernel-conversion 3-pass ----------------
__global__ __launch_bounds__(NTH) void knn_phase1_cvt_kernel(
    const float* __restrict__ Q, const float* __restrict__ C,
    const float* __restrict__ q2g, const float* __restrict__ c2g,
    float* __restrict__ tkd, int* __restrict__ tki,
    int n1, int n2, int chunk, int nc)
{
  extern __shared__ char smem[];
  unsigned short* qh = (unsigned short*)smem;
  unsigned short* ql = qh + 64*64;
  unsigned short* ch = ql + 64*64;
  unsigned short* cl = ch + 512*64;
  float* dl = (float*)(smem + 147456);

  const int tid  = threadIdx.x;
  const int w    = tid >> 6;
  const int l    = tid & 63;
  const int l31  = l & 31;
  const int half = l >> 5;
  const int mbase   = blockIdx.x * MT;
  const int chunkid = blockIdx.y;
  const int cbase0  = chunkid * chunk;
  const int cend    = min(cbase0 + chunk, n2);

  float q2w[8];
  #pragma unroll
  for (int g = 0; g < 8; ++g) q2w[g] = q2g[min(mbase + g*8 + w, n1 - 1)];

  float listd[8]; int listi[8]; float wd4[8]; int wi4[8];
  #pragma unroll
  for (int g = 0; g < 8; ++g) { listd[g]=INF; listi[g]=0x7fffffff; wd4[g]=INF; wi4[g]=0x7fffffff; }

  const int srow = tid >> 3;
  const int sk8  = (tid & 7) * 8;
  const int su   = (tid & 7);

  float4 cva[8][2], qva[2];
  auto LOADR = [&](int kb, int cb) {
    {
      int gr = min(mbase + srow, n1 - 1);
      const float4* p = (const float4*)(Q + (size_t)gr * D + kb*KC + sk8);
      qva[0] = p[0]; qva[1] = p[1];
    }
    #pragma unroll
    for (int r = 0; r < 8; ++r) {
      int gn = cb + srow + 64*r;
      if (gn < cend) {
        const float4* p = (const float4*)(C + (size_t)gn * D + kb*KC + sk8);
        cva[r][0] = p[0]; cva[r][1] = p[1];
      } else {
        cva[r][0] = make_float4(0.f,0.f,0.f,0.f);
        cva[r][1] = make_float4(0.f,0.f,0.f,0.f);
      }
    }
  };
  auto STORE = [&]() {
    int4 hi, lo;
    {
      int idx = srow*64 + (su ^ (srow & 7))*8;
      cvt8(qva[0], qva[1], hi, lo);
      *(int4*)(qh + idx) = hi; *(int4*)(ql + idx) = lo;
    }
    #pragma unroll
    for (int r = 0; r < 8; ++r) {
      int row = srow + 64*r;
      int idx = row*64 + (su ^ (row & 7))*8;
      cvt8(cva[r][0], cva[r][1], hi, lo);
      *(int4*)(ch + idx) = hi; *(int4*)(cl + idx) = lo;
    }
  };

  f32x16 zf;
  #pragma unroll
  for (int e = 0; e < 16; ++e) zf[e] = 0.f;

  const int nsteps = (cend - cbase0 + NT - 1) / NT;
  LOADR(0, cbase0);

  for (int nt = 0; nt < nsteps; ++nt) {
    const int cbase = cbase0 + nt * NT;
    f32x16 acc[2][2];
    #pragma unroll
    for (int rt = 0; rt < 2; ++rt)
      #pragma unroll
      for (int ct = 0; ct < 2; ++ct) acc[rt][ct] = zf;

    for (int kb = 0; kb < D/KC; ++kb) {
      __syncthreads();
      STORE();
      __syncthreads();
      if (kb + 1 < D/KC)        LOADR(kb + 1, cbase);
      else if (nt + 1 < nsteps) LOADR(0, cbase + NT);

      #pragma unroll
      for (int ks = 0; ks < 4; ++ks) {
        const int u = 2*ks + half;
        s16x8 qf[2][2], cf[2][2];
        #pragma unroll
        for (int rt = 0; rt < 2; ++rt) {
          int r = rt*32 + l31;
          int idx = r*64 + (u ^ (r & 7))*8;
          qf[rt][0] = *(const s16x8*)(qh + idx);
          qf[rt][1] = *(const s16x8*)(ql + idx);
        }
        #pragma unroll
        for (int ct = 0; ct < 2; ++ct) {
          int c = w*64 + ct*32 + l31;
          int idx = c*64 + (u ^ (c & 7))*8;
          cf[ct][0] = *(const s16x8*)(ch + idx);
          cf[ct][1] = *(const s16x8*)(cl + idx);
        }
        #pragma unroll
        for (int rt = 0; rt < 2; ++rt)
          #pragma unroll
          for (int ct = 0; ct < 2; ++ct) {
            acc[rt][ct] = __builtin_amdgcn_mfma_f32_32x32x16_bf16(qf[rt][0], cf[ct][0], acc[rt][ct], 0, 0, 0);
            acc[rt][ct] = __builtin_amdgcn_mfma_f32_32x32x16_bf16(qf[rt][0], cf[ct][1], acc[rt][ct], 0, 0, 0);
            acc[rt][ct] = __builtin_amdgcn_mfma_f32_32x32x16_bf16(qf[rt][1], cf[ct][0], acc[rt][ct], 0, 0, 0);
          }
      }
    }

    float c2v[2]; int vld[2];
    #pragma unroll
    for (int ct = 0; ct < 2; ++ct) {
      int gc = cbase + w*64 + ct*32 + l31;
      vld[ct] = (gc < cend);
      c2v[ct] = vld[ct] ? c2g[gc] : 0.f;
    }
    #pragma unroll
    for (int g = 0; g < 8; ++g) {
      const int rt = g >> 2, qq = g & 3;
      #pragma unroll
      for (int jj = 0; jj < 4; ++jj)
        #pragma unroll
        for (int ct = 0; ct < 2; ++ct) {
          float a = acc[rt][ct][4*qq + jj];
          float s = c2v[ct] - 2.f * a;
          dl[(4*half + jj)*512 + w*64 + ct*32 + l31] = vld[ct] ? s : INF;
        }
      __syncthreads();
      const float q2u = q2w[g];
      #pragma unroll
      for (int j2 = 0; j2 < 8; ++j2) {
        float sv = dl[w*512 + l + 64*j2];
        float dv = sqrtf(fmaxf(q2u + sv, 0.f));
        unsigned long long mask = __ballot(dv < wd4[g]);
        while (mask) {
          int L = __ffsll(mask) - 1; mask &= mask - 1;
          float dnew = __shfl(dv, L, 64);
          int ci = cbase + 64*j2 + L;
          if ((dnew < wd4[g]) || (dnew == wd4[g] && ci < wi4[g])) {
            bool isw = (l < 32) && (listd[g] == wd4[g]) && (listi[g] == wi4[g]);
            int wl = __ffsll(__ballot(isw)) - 1;
            if (l == wl) { listd[g] = dnew; listi[g] = ci; }
            worst_reduce((l < 32) ? listd[g] : -1.f,
                         (l < 32) ? listi[g] : -1, wd4[g], wi4[g]);
          }
        }
      }
      __syncthreads();
    }
  }

  #pragma unroll
  for (int g = 0; g < 8; ++g) {
    int gq = mbase + g*8 + w;
    float d = listd[g]; int i = listi[g];
    int rank = 0;
    #pragma unroll
    for (int j = 0; j < KSEL; ++j) {
      float dj = __shfl(listd[g], j, 64);
      int   ij = __shfl(listi[g], j, 64);
      rank += (dj < d) || (dj == d && ij < i);
    }
    if (l < 32 && gq < n1) {
      size_t o = ((size_t)gq * nc + chunkid) * KSEL + rank;
      tkd[o] = d; tki[o] = i;
    }
  }
}

// ---------------- Phase 2: merge + exact rescore + cosine ----------------
__global__ __launch_bounds__(256) void knn_phase2_kernel(
    const float* __restrict__ Q0, const float* __restrict__ Q1,
    const float* __restrict__ C0, const float* __restrict__ C1,
    const float* __restrict__ q2g, const float* __restrict__ c2g,
    const float* __restrict__ tkd, const int* __restrict__ tki,
    float* __restrict__ out, int n1, int n2, int nc)
{
  __shared__ float q0s[D], q1s[D];
  __shared__ float pd[256]; __shared__ int pi[256];
  __shared__ float nd[NSELMX]; __shared__ int ni[NSELMX];
  __shared__ float de[NSELMX];
  __shared__ int   fi[KSEL];
  __shared__ float cosj[KSEL];
  __shared__ float red0[4], red1[4], qn[2];

  const int q = blockIdx.x, tid = threadIdx.x;
  const int npool = nc * KSEL;
  const int nsel  = (NSELMX < npool) ? NSELMX : npool;

  if (tid < 128) ((float4*)q0s)[tid] = ((const float4*)(Q0 + (size_t)q*D))[tid];
  else           ((float4*)q1s)[tid-128] = ((const float4*)(Q1 + (size_t)q*D))[tid-128];
  if (tid < npool) { pd[tid] = tkd[(size_t)q*npool + tid]; pi[tid] = tki[(size_t)q*npool + tid]; }
  __syncthreads();

  float a0 = q0s[tid], b0 = q0s[tid+256], a1 = q1s[tid], b1 = q1s[tid+256];
  float s0 = a0*a0 + b0*b0, s1 = a1*a1 + b1*b1;
  #pragma unroll
  for (int o = 32; o > 0; o >>= 1) { s0 += __shfl_down(s0, o, 64); s1 += __shfl_down(s1, o, 64); }
  int lane = tid & 63, wid = tid >> 6;
  if (lane == 0) { red0[wid] = s0; red1[wid] = s1; }

  if (tid < npool) {
    float dm = pd[tid]; int im = pi[tid]; int rank = 0;
    for (int j = 0; j < npool; ++j) {
      float dj = pd[j]; int ij = pi[j];
      rank += (dj < dm) || (dj == dm && ij < im);
    }
    if (rank < nsel) { nd[rank] = dm; ni[rank] = im; }
  }
  __syncthreads();
  if (tid == 0) {
    qn[0] = fmaxf(sqrtf(red0[0]+red0[1]+red0[2]+red0[3]), CEPS);
    qn[1] = fmaxf(sqrtf(red1[0]+red1[1]+red1[2]+red1[3]), CEPS);
  }

  const float q2q = q2g[q];
  const int ll = tid & 7;
  for (int base = 0; base < NSELMX; base += 32) {
    int g = base + (tid >> 3);
    if (g < nsel) {
      int ix = ni[g];
      bool okx = (ix >= 0 && ix < n2);
      int ixc = okx ? ix : 0;
      const float4* r0  = (const float4*)(C0 + (size_t)ixc * D);
      const float4* q04 = (const float4*)q0s;
      float dot = 0.f;
      #pragma unroll
      for (int r = 0; r < 16; ++r) {
        float4 v = r0[r*8 + ll], u = q04[r*8 + ll];
        dot = fmaf(v.x,u.x, fmaf(v.y,u.y, fmaf(v.z,u.z, fmaf(v.w,u.w, dot))));
      }
      #pragma unroll
      for (int o = 4; o > 0; o >>= 1) dot += __shfl_xor(dot, o, 64);
      if (ll == 0) de[g] = okx ? sqrtf(fmaxf(q2q + c2g[ixc] - 2.f*dot, 0.f)) : INF;
    }
  }
  __syncthreads();

  if (tid < nsel) {
    float dm = de[tid]; int im = ni[tid]; int rank = 0;
    for (int j = 0; j < nsel; ++j) {
      float dj = de[j]; int ij = ni[j];
      rank += (dj < dm) || (dj == dm && ij < im);
    }
    if (rank < KSEL) fi[rank] = im;
  }
  __syncthreads();

  const int g = tid >> 3;
  int ix = fi[g];
  ix = (ix >= 0 && ix < n2) ? ix : 0;
  const float4* r0  = (const float4*)(C0 + (size_t)ix * D);
  const float4* r1  = (const float4*)(C1 + (size_t)ix * D);
  const float4* q04 = (const float4*)q0s;
  const float4* q14 = (const float4*)q1s;
  float dot0 = 0.f, nn0 = 0.f, dot1 = 0.f, nn1 = 0.f;
  #pragma unroll
  for (int r = 0; r < 16; ++r) {
    int e4 = r*8 + ll;
    float4 v0 = r0[e4], qv0 = q04[e4];
    dot0 = fmaf(v0.x,qv0.x, fmaf(v0.y,qv0.y, fmaf(v0.z,qv0.z, fmaf(v0.w,qv0.w, dot0))));
    nn0  = fmaf(v0.x,v0.x,  fmaf(v0.y,v0.y,  fmaf(v0.z,v0.z,  fmaf(v0.w,v0.w,  nn0))));
    float4 v1 = r1[e4], qv1 = q14[e4];
    dot1 = fmaf(v1.x,qv1.x, fmaf(v1.y,qv1.y, fmaf(v1.z,qv1.z, fmaf(v1.w,qv1.w, dot1))));
    nn1  = fmaf(v1.x,v1.x,  fmaf(v1.y,v1.y,  fmaf(v1.z,v1.z,  fmaf(v1.w,v1.w,  nn1))));
  }
  #pragma unroll
  for (int o = 4; o > 0; o >>= 1) {
    dot0 += __shfl_xor(dot0, o, 64); nn0 += __shfl_xor(nn0, o, 64);
    dot1 += __shfl_xor(dot1, o, 64); nn1 += __shfl_xor(nn1, o, 64);
  }
  if (ll == 0) {
    float c0 = dot0 / (fmaxf(sqrtf(nn0), CEPS) * qn[0]);
    float c1 = dot1 / (fmaxf(sqrtf(nn1), CEPS) * qn[1]);
    float cv = (c0 > c1) ? c0 : c1;
    out[(size_t)q * KSEL + g] = cv;
    cosj[g] = cv;
  }
  __syncthreads();
  if (tid == 0) {
    float s = 0.f;
    #pragma unroll
    for (int j = 0; j < KSEL; ++j) s += cosj[j];
    out[(size_t)n1 * KSEL + q] = s * (1.f / KSEL);
  }
}

// ---------------- launch ----------------
extern "C" void kernel_launch(void* const* d_in, const int* in_sizes, int n_in,
                              void* d_out, int out_size, void* d_ws, size_t ws_size,
                              hipStream_t stream)
{
  const float* Q0 = (const float*)d_in[0];
  const float* Q1 = (const float*)d_in[1];
  const float* C0 = (const float*)d_in[2];
  const float* C1 = (const float*)d_in[3];
  const int n1 = in_sizes[0] / D;   // 2048
  const int n2 = in_sizes[2] / D;   // 50000
  float* out = (float*)d_out;
  if (n1 <= 0 || n2 <= 0) return;

  char* wsb = (char*)d_ws;
  size_t c2n = ((size_t)n2 + 127) & ~(size_t)127;
  size_t q2n = ((size_t)n1 + 127) & ~(size_t)127;

  // fast-path ws layout
  size_t off_c2  = 0;
  size_t off_q2  = off_c2 + c2n*4;
  size_t off_tkd = off_q2 + q2n*4;
  size_t off_tki = off_tkd + (size_t)n1*NCF*KSEL*4;
  size_t off_cb  = (off_tki + (size_t)n1*NCF*KSEL*4 + 255) & ~(size_t)255;
  size_t off_qb  = off_cb + ((size_t)n2 + 512)*D*2;
  size_t need    = off_qb + (size_t)n1*D*2;
  bool fast = (ws_size >= need);

  if (fast) {
    float* c2  = (float*)(wsb + off_c2);
    float* q2  = (float*)(wsb + off_q2);
    float* tkd = (float*)(wsb + off_tkd);
    int*   tki = (int*)(wsb + off_tki);
    unsigned short* Cb = (unsigned short*)(wsb + off_cb);
    unsigned short* Qb = (unsigned short*)(wsb + off_qb);

    int n2e8 = n2 * (D/8), n1e8 = n1 * (D/8);
    precvt_kernel<<<(n2e8 + n1e8 + 255)/256, 256, 0, stream>>>(C0, Q0, Cb, Qb, n2e8, n1e8);
    rows_sumsq_kernel<<<(n2 + n1 + 3)/4, 256, 0, stream>>>(C0, Q0, c2, q2, n2, n1);

    const int chunk  = (n2 + NCF - 1) / NCF;
    const int mtiles = (n1 + MT - 1) / MT;
    (void)hipFuncSetAttribute((const void*)knn_phase1_bf_kernel,
                              hipFuncAttributeMaxDynamicSharedMemorySize, 163840);
    knn_phase1_bf_kernel<<<dim3(mtiles, NCF), NTH, 163840, stream>>>(
        Qb, Cb, q2, c2, tkd, tki, n1, n2, chunk, NCF);
    knn_phase2_kernel<<<n1, 256, 0, stream>>>(Q0, Q1, C0, C1, q2, c2, tkd, tki, out, n1, n2, NCF);
  } else {
    // fallback: R4 layout + in-kernel conversion
    float* wsf = (float*)d_ws;
    int nc = 8;
    while (nc > 1 && (c2n + q2n + (size_t)n1 * nc * KSEL * 2) * 4 > ws_size) nc >>= 1;
    float* c2  = wsf;
    float* q2  = wsf + c2n;
    float* tkd = wsf + c2n + q2n;
    int*   tki = (int*)(wsf + c2n + q2n + (size_t)n1 * nc * KSEL);

    rows_sumsq_kernel<<<(n2 + n1 + 3)/4, 256, 0, stream>>>(C0, Q0, c2, q2, n2, n1);
    const int chunk  = (n2 + nc - 1) / nc;
    const int mtiles = (n1 + MT - 1) / MT;
    (void)hipFuncSetAttribute((const void*)knn_phase1_cvt_kernel,
                              hipFuncAttributeMaxDynamicSharedMemorySize, 163840);
    knn_phase1_cvt_kernel<<<dim3(mtiles, nc), NTH, 163840, stream>>>(
        Q0, C0, q2, c2, tkd, tki, n1, n2, chunk, nc);
    knn_phase2_kernel<<<n1, 256, 0, stream>>>(Q0, Q1, C0, C1, q2, c2, tkd, tki, out, n1, n2, nc);
  }
}

// Round 7
// 536.332 us; speedup vs baseline: 12.1660x; 2.6992x over previous
//
#include <hip/hip_runtime.h>
#include <math.h>

// KNN (L2 top-32) + cosine re-rank, MI355X.
// P-1: precvt — one-time fp32 -> bf16(hi, RTN) tables for C0/Q0 in ws.
// P0 : row sum-of-squares (exact fp32).
// P1 : 1-pass bf16 MFMA distance GEMM (32x32x16), 64q x 512c tiles, KC=64,
//      global_load_lds DMA staging, double-buffered LDS, counted vmcnt(9).
//      Selection: per-lane register top-5 (packed u64, pure VALU hot loop),
//      end-of-chunk pivot+compact+rank -> per-chunk noisy top-32 (d^2 keys).
//      sel buffer lives in the dead qh/ch region: 512 entries/wave (max Ns=320).
// P2 : merge 8x32 -> noisy top-64 -> EXACT fp32 rescore -> exact top-32 -> cosine.
// Fallback (small ws): R4's in-kernel-conversion 3-pass kernel (proven).

#define D       512
#define MT      64
#define NT      512
#define KC      64
#define NTH     512
#define KSEL    32
#define NSELMX  64
#define NCF     8      // chunks, fast path
#define TOPL    5      // per-lane register list length
#define CEPS    1e-8f
#define INF     __builtin_inff()

using s16x8  = __attribute__((ext_vector_type(8)))  short;
using f32x16 = __attribute__((ext_vector_type(16))) float;

__device__ __forceinline__ void async16(const void* g, void* s) {
  __builtin_amdgcn_global_load_lds(
      (const __attribute__((address_space(1))) unsigned int*)g,
      (__attribute__((address_space(3))) unsigned int*)s, 16, 0, 0);
}

// two fp32 -> packed bf16 pair (RTN)
__device__ __forceinline__ unsigned int bfhi2(float x0, float x1) {
  unsigned int u0 = __float_as_uint(x0), u1 = __float_as_uint(x1);
  u0 = (u0 + 0x7fffu + ((u0 >> 16) & 1u)) >> 16;
  u1 = (u1 + 0x7fffu + ((u1 >> 16) & 1u)) & 0xffff0000u;
  return u0 | u1;
}

// ---------------- P-1: one-time bf16 conversion ----------------
__global__ __launch_bounds__(256) void precvt_kernel(
    const float* __restrict__ C, const float* __restrict__ Q,
    unsigned short* __restrict__ Cb, unsigned short* __restrict__ Qb,
    int n2e8, int n1e8)
{
  int i = blockIdx.x * 256 + threadIdx.x;
  const float* src; unsigned short* dst;
  if (i < n2e8) { src = C + (size_t)i * 8; dst = Cb + (size_t)i * 8; }
  else if (i < n2e8 + n1e8) {
    int r = i - n2e8;
    src = Q + (size_t)r * 8; dst = Qb + (size_t)r * 8;
  } else return;
  float4 a = ((const float4*)src)[0], b = ((const float4*)src)[1];
  int4 h;
  h.x = (int)bfhi2(a.x, a.y); h.y = (int)bfhi2(a.z, a.w);
  h.z = (int)bfhi2(b.x, b.y); h.w = (int)bfhi2(b.z, b.w);
  *(int4*)dst = h;
}

// ---------------- Phase 0 ----------------
__global__ __launch_bounds__(256) void rows_sumsq_kernel(
    const float* __restrict__ C, const float* __restrict__ Q,
    float* __restrict__ c2, float* __restrict__ q2, int n2, int n1)
{
  int wid  = threadIdx.x >> 6;
  int lane = threadIdx.x & 63;
  int row  = blockIdx.x * 4 + wid;
  const float* src; float* dst;
  if (row < n2) { src = C + (size_t)row * D; dst = c2 + row; }
  else { int r = row - n2; if (r >= n1) return; src = Q + (size_t)r * D; dst = q2 + r; }
  const float4* s4 = (const float4*)src;
  float4 a = s4[lane], b = s4[lane + 64];
  float s = a.x*a.x + a.y*a.y + a.z*a.z + a.w*a.w
          + b.x*b.x + b.y*b.y + b.z*b.z + b.w*b.w;
  #pragma unroll
  for (int o = 32; o > 0; o >>= 1) s += __shfl_down(s, o, 64);
  if (lane == 0) *dst = s;
}

// lexicographic max of (d,i) over lanes 0..31 (fallback kernel only)
__device__ inline void worst_reduce(float dIn, int iIn, float& wd, int& wi) {
  float dd = dIn; int ii = iIn;
  #pragma unroll
  for (int o = 1; o <= 16; o <<= 1) {
    float dp = __shfl_xor(dd, o, 64);
    int   ip = __shfl_xor(ii, o, 64);
    bool take = (dp > dd) || (dp == dd && ip > ii);
    dd = take ? dp : dd; ii = take ? ip : ii;
  }
  wd = __shfl(dd, 0, 64); wi = __shfl(ii, 0, 64);
}

// fp32 -> (bf16_hi, bf16_lo) split (fallback kernel only)
__device__ inline void cvt8(const float4 a, const float4 b, int4& hi, int4& lo) {
  float x[8] = {a.x, a.y, a.z, a.w, b.x, b.y, b.z, b.w};
  unsigned int hw[8], lw[8];
  #pragma unroll
  for (int j = 0; j < 8; ++j) {
    unsigned int ux = __float_as_uint(x[j]);
    unsigned int rh = (ux + 0x7fffu + ((ux >> 16) & 1u)) & 0xffff0000u;
    float rl = x[j] - __uint_as_float(rh);
    unsigned int ul = __float_as_uint(rl);
    hw[j] = rh >> 16;
    lw[j] = (ul + 0x7fffu + ((ul >> 16) & 1u)) >> 16;
  }
  hi = make_int4((int)(hw[0]|(hw[1]<<16)), (int)(hw[2]|(hw[3]<<16)),
                 (int)(hw[4]|(hw[5]<<16)), (int)(hw[6]|(hw[7]<<16)));
  lo = make_int4((int)(lw[0]|(lw[1]<<16)), (int)(lw[2]|(lw[3]<<16)),
                 (int)(lw[4]|(lw[5]<<16)), (int)(lw[6]|(lw[7]<<16)));
}

// ---------------- Phase 1 (fast): DMA-staged 1-pass bf16 MFMA ----------------
// LDS: qh dbuf 2x8K | ch dbuf 2x64K | dl [8][512] 16K = 160K
// end-of-chunk sel buffer: reuses qh/ch region (dead), 512 u64/wave.
__global__ __launch_bounds__(NTH, 2) void knn_phase1_bf_kernel(
    const unsigned short* __restrict__ Qb, const unsigned short* __restrict__ Cb,
    const float* __restrict__ q2g, const float* __restrict__ c2g,
    float* __restrict__ tkd, int* __restrict__ tki,
    int n1, int n2, int chunk, int nc)
{
  extern __shared__ char smem[];
  unsigned short* qh = (unsigned short*)smem;                // 2 x [64][64]
  unsigned short* ch = qh + 2*64*64;                         // 2 x [512][64]
  float* dl = (float*)(smem + 147456);                       // [8][512]

  const int tid  = threadIdx.x;
  const int w    = tid >> 6;
  const int l    = tid & 63;
  const int l31  = l & 31;
  const int half = l >> 5;
  const int mbase   = blockIdx.x * MT;
  const int chunkid = blockIdx.y;
  const int cbase0  = chunkid * chunk;
  const int cend    = min(cbase0 + chunk, n2);

  float q2w[8];
  #pragma unroll
  for (int g = 0; g < 8; ++g) q2w[g] = q2g[min(mbase + g*8 + w, n1 - 1)];

  // per-lane register top-TOPL lists, one per owned row (row g*8+w), sorted asc
  unsigned long long vv[8][TOPL];
  #pragma unroll
  for (int g = 0; g < 8; ++g)
    #pragma unroll
    for (int t = 0; t < TOPL; ++t) vv[g][t] = 0xffffffffffffffffULL;

  const int lrow = l >> 3;                 // row-within-8 of this lane
  const int su   = (l & 7) ^ lrow;         // pre-swizzled source unit

  auto STAGE = [&](int buf, int kb, int cb) {
    {
      int gm = min(mbase + w*8 + lrow, n1 - 1);
      const unsigned short* src = Qb + (size_t)gm * D + kb*KC + su*8;
      unsigned short* dst = qh + buf*(64*64) + (w*8)*64;     // wave-uniform base
      async16(src, dst);
    }
    #pragma unroll
    for (int i = 0; i < 8; ++i) {
      int gn = cb + w*64 + i*8 + lrow;                       // may overrun cend (padded)
      const unsigned short* src = Cb + (size_t)gn * D + kb*KC + su*8;
      unsigned short* dst = ch + buf*(512*64) + (w*64 + i*8)*64;
      async16(src, dst);
    }
  };

  f32x16 zf;
  #pragma unroll
  for (int e = 0; e < 16; ++e) zf[e] = 0.f;

  const int nsteps = (cend - cbase0 + NT - 1) / NT;
  int b = 0;
  STAGE(0, 0, cbase0);
  __syncthreads();            // drain prologue

  for (int nt = 0; nt < nsteps; ++nt) {
    const int cbase = cbase0 + nt * NT;
    f32x16 acc[2][2];
    #pragma unroll
    for (int rt = 0; rt < 2; ++rt)
      #pragma unroll
      for (int ct = 0; ct < 2; ++ct) acc[rt][ct] = zf;

    for (int kb = 0; kb < D/KC; ++kb) {
      if (kb + 1 < D/KC) {
        STAGE(b^1, kb+1, cbase);
        asm volatile("s_waitcnt vmcnt(9)" ::: "memory");
      } else if (nt + 1 < nsteps) {
        STAGE(b^1, 0, cbase + NT);
        asm volatile("s_waitcnt vmcnt(9)" ::: "memory");
      } else {
        asm volatile("s_waitcnt vmcnt(0)" ::: "memory");
      }
      __builtin_amdgcn_s_barrier();
      __builtin_amdgcn_sched_barrier(0);

      const unsigned short* qb  = qh + b*(64*64);
      const unsigned short* cbf = ch + b*(512*64);
      #pragma unroll
      for (int ks = 0; ks < 4; ++ks) {
        const int u = 2*ks + half;
        s16x8 qf[2], cf[2];
        #pragma unroll
        for (int rt = 0; rt < 2; ++rt) {
          int r = rt*32 + l31;
          qf[rt] = *(const s16x8*)(qb + r*64 + (u ^ (r & 7))*8);
        }
        #pragma unroll
        for (int ct = 0; ct < 2; ++ct) {
          int c = w*64 + ct*32 + l31;
          cf[ct] = *(const s16x8*)(cbf + c*64 + (u ^ (c & 7))*8);
        }
        #pragma unroll
        for (int rt = 0; rt < 2; ++rt)
          #pragma unroll
          for (int ct = 0; ct < 2; ++ct)
            acc[rt][ct] = __builtin_amdgcn_mfma_f32_32x32x16_bf16(qf[rt], cf[ct], acc[rt][ct], 0, 0, 0);
      }
      asm volatile("s_waitcnt lgkmcnt(0)" ::: "memory");
      __builtin_amdgcn_s_barrier();
      __builtin_amdgcn_sched_barrier(0);
      b ^= 1;
    }

    // epilogue: s = c2 - 2*dot -> dl (8-row groups); per-lane register filter
    float c2v[2]; int vld[2];
    #pragma unroll
    for (int ct = 0; ct < 2; ++ct) {
      int gc = cbase + w*64 + ct*32 + l31;
      vld[ct] = (gc < cend);
      c2v[ct] = vld[ct] ? c2g[gc] : 0.f;
    }
    #pragma unroll
    for (int g = 0; g < 8; ++g) {
      const int rt = g >> 2, qq = g & 3;
      #pragma unroll
      for (int jj = 0; jj < 4; ++jj)
        #pragma unroll
        for (int ct = 0; ct < 2; ++ct) {
          float a = acc[rt][ct][4*qq + jj];
          float s = c2v[ct] - 2.f * a;
          dl[(4*half + jj)*512 + w*64 + ct*32 + l31] = vld[ct] ? s : INF;
        }
      __syncthreads();
      // wave w filters row g*8+w: pure-VALU per-lane top-TOPL insert
      const float q2u = q2w[g];
      #pragma unroll
      for (int j2 = 0; j2 < 8; ++j2) {
        float sv  = dl[w*512 + l + 64*j2];
        float d2v = fmaxf(q2u + sv, 0.f);            // INF stays INF
        unsigned int kbit = __float_as_uint(d2v);
        unsigned int ci = (kbit != 0x7f800000u) ? (unsigned)(cbase + 64*j2 + l)
                                                : 0x7fffffffu;
        unsigned long long e = ((unsigned long long)kbit << 32) | ci;
        if (e < vv[g][TOPL-1]) {
          vv[g][TOPL-1] = e;
          #pragma unroll
          for (int t = TOPL-1; t > 0; --t) {
            unsigned long long lo = vv[g][t-1] < vv[g][t] ? vv[g][t-1] : vv[g][t];
            unsigned long long hi = vv[g][t-1] < vv[g][t] ? vv[g][t]   : vv[g][t-1];
            vv[g][t-1] = lo; vv[g][t] = hi;
          }
        }
      }
      __syncthreads();
    }
  }

  // ---- end-of-chunk selection: pivot + compact + rank (per wave) ----
  // sel lives in the dead qh/ch region: 512 u64 per wave (max Ns = 320).
  unsigned long long* sel = (unsigned long long*)smem + (size_t)w * 512;
  const unsigned long long mlt = (l == 0) ? 0ull : ((~0ull) >> (64 - l)); // lanes < me
  __syncthreads();   // everyone past the main loop before qh/ch reuse
  #pragma unroll
  for (int g = 0; g < 8; ++g) {
    // pivot key = max over lanes of key(vv[g][0]); guarantees >=64 survivors
    unsigned int pk = (unsigned int)(vv[g][0] >> 32);
    #pragma unroll
    for (int o = 1; o < 64; o <<= 1) {
      unsigned int other = (unsigned int)__shfl_xor((int)pk, o, 64);
      pk = (other > pk) ? other : pk;
    }
    int cnt = 0;
    #pragma unroll
    for (int t = 0; t < TOPL; ++t) cnt += ((unsigned int)(vv[g][t] >> 32) <= pk) ? 1 : 0;
    unsigned long long b0 = __ballot(cnt & 1);
    unsigned long long b1 = __ballot(cnt & 2);
    unsigned long long b2 = __ballot(cnt & 4);
    int pre = __popcll(b0 & mlt) + 2*__popcll(b1 & mlt) + 4*__popcll(b2 & mlt);
    int Ns  = __popcll(b0) + 2*__popcll(b1) + 4*__popcll(b2);
    #pragma unroll
    for (int t = 0; t < TOPL; ++t)
      if (t < cnt) sel[pre + t] = vv[g][t];
    asm volatile("s_waitcnt lgkmcnt(0)" ::: "memory");
    __builtin_amdgcn_sched_barrier(0);
    int rk[TOPL];
    #pragma unroll
    for (int t = 0; t < TOPL; ++t) rk[t] = 0;
    for (int j = 0; j < Ns; ++j) {
      unsigned long long e = sel[j];
      #pragma unroll
      for (int t = 0; t < TOPL; ++t) rk[t] += (e < vv[g][t]) ? 1 : 0;
    }
    int gq = mbase + g*8 + w;
    if (gq < n1) {
      #pragma unroll
      for (int t = 0; t < TOPL; ++t)
        if (t < cnt && rk[t] < KSEL) {
          size_t o = ((size_t)gq * nc + chunkid) * KSEL + rk[t];
          tkd[o] = __uint_as_float((unsigned int)(vv[g][t] >> 32));
          tki[o] = (int)(unsigned int)(vv[g][t] & 0xffffffffu);
        }
    }
  }
}

// ---------------- Phase 1 (fallback): R4 in-kernel-conversion 3-pass ----------------
__global__ __launch_bounds__(NTH) void knn_phase1_cvt_kernel(
    const float* __restrict__ Q, const float* __restrict__ C,
    const float* __restrict__ q2g, const float* __restrict__ c2g,
    float* __restrict__ tkd, int* __restrict__ tki,
    int n1, int n2, int chunk, int nc)
{
  extern __shared__ char smem[];
  unsigned short* qh = (unsigned short*)smem;
  unsigned short* ql = qh + 64*64;
  unsigned short* ch = ql + 64*64;
  unsigned short* cl = ch + 512*64;
  float* dl = (float*)(smem + 147456);

  const int tid  = threadIdx.x;
  const int w    = tid >> 6;
  const int l    = tid & 63;
  const int l31  = l & 31;
  const int half = l >> 5;
  const int mbase   = blockIdx.x * MT;
  const int chunkid = blockIdx.y;
  const int cbase0  = chunkid * chunk;
  const int cend    = min(cbase0 + chunk, n2);

  float q2w[8];
  #pragma unroll
  for (int g = 0; g < 8; ++g) q2w[g] = q2g[min(mbase + g*8 + w, n1 - 1)];

  float listd[8]; int listi[8]; float wd4[8]; int wi4[8];
  #pragma unroll
  for (int g = 0; g < 8; ++g) { listd[g]=INF; listi[g]=0x7fffffff; wd4[g]=INF; wi4[g]=0x7fffffff; }

  const int srow = tid >> 3;
  const int sk8  = (tid & 7) * 8;
  const int su   = (tid & 7);

  float4 cva[8][2], qva[2];
  auto LOADR = [&](int kb, int cb) {
    {
      int gr = min(mbase + srow, n1 - 1);
      const float4* p = (const float4*)(Q + (size_t)gr * D + kb*KC + sk8);
      qva[0] = p[0]; qva[1] = p[1];
    }
    #pragma unroll
    for (int r = 0; r < 8; ++r) {
      int gn = cb + srow + 64*r;
      if (gn < cend) {
        const float4* p = (const float4*)(C + (size_t)gn * D + kb*KC + sk8);
        cva[r][0] = p[0]; cva[r][1] = p[1];
      } else {
        cva[r][0] = make_float4(0.f,0.f,0.f,0.f);
        cva[r][1] = make_float4(0.f,0.f,0.f,0.f);
      }
    }
  };
  auto STORE = [&]() {
    int4 hi, lo;
    {
      int idx = srow*64 + (su ^ (srow & 7))*8;
      cvt8(qva[0], qva[1], hi, lo);
      *(int4*)(qh + idx) = hi; *(int4*)(ql + idx) = lo;
    }
    #pragma unroll
    for (int r = 0; r < 8; ++r) {
      int row = srow + 64*r;
      int idx = row*64 + (su ^ (row & 7))*8;
      cvt8(cva[r][0], cva[r][1], hi, lo);
      *(int4*)(ch + idx) = hi; *(int4*)(cl + idx) = lo;
    }
  };

  f32x16 zf;
  #pragma unroll
  for (int e = 0; e < 16; ++e) zf[e] = 0.f;

  const int nsteps = (cend - cbase0 + NT - 1) / NT;
  LOADR(0, cbase0);

  for (int nt = 0; nt < nsteps; ++nt) {
    const int cbase = cbase0 + nt * NT;
    f32x16 acc[2][2];
    #pragma unroll
    for (int rt = 0; rt < 2; ++rt)
      #pragma unroll
      for (int ct = 0; ct < 2; ++ct) acc[rt][ct] = zf;

    for (int kb = 0; kb < D/KC; ++kb) {
      __syncthreads();
      STORE();
      __syncthreads();
      if (kb + 1 < D/KC)        LOADR(kb + 1, cbase);
      else if (nt + 1 < nsteps) LOADR(0, cbase + NT);

      #pragma unroll
      for (int ks = 0; ks < 4; ++ks) {
        const int u = 2*ks + half;
        s16x8 qf[2][2], cf[2][2];
        #pragma unroll
        for (int rt = 0; rt < 2; ++rt) {
          int r = rt*32 + l31;
          int idx = r*64 + (u ^ (r & 7))*8;
          qf[rt][0] = *(const s16x8*)(qh + idx);
          qf[rt][1] = *(const s16x8*)(ql + idx);
        }
        #pragma unroll
        for (int ct = 0; ct < 2; ++ct) {
          int c = w*64 + ct*32 + l31;
          int idx = c*64 + (u ^ (c & 7))*8;
          cf[ct][0] = *(const s16x8*)(ch + idx);
          cf[ct][1] = *(const s16x8*)(cl + idx);
        }
        #pragma unroll
        for (int rt = 0; rt < 2; ++rt)
          #pragma unroll
          for (int ct = 0; ct < 2; ++ct) {
            acc[rt][ct] = __builtin_amdgcn_mfma_f32_32x32x16_bf16(qf[rt][0], cf[ct][0], acc[rt][ct], 0, 0, 0);
            acc[rt][ct] = __builtin_amdgcn_mfma_f32_32x32x16_bf16(qf[rt][0], cf[ct][1], acc[rt][ct], 0, 0, 0);
            acc[rt][ct] = __builtin_amdgcn_mfma_f32_32x32x16_bf16(qf[rt][1], cf[ct][0], acc[rt][ct], 0, 0, 0);
          }
      }
    }

    float c2v[2]; int vld[2];
    #pragma unroll
    for (int ct = 0; ct < 2; ++ct) {
      int gc = cbase + w*64 + ct*32 + l31;
      vld[ct] = (gc < cend);
      c2v[ct] = vld[ct] ? c2g[gc] : 0.f;
    }
    #pragma unroll
    for (int g = 0; g < 8; ++g) {
      const int rt = g >> 2, qq = g & 3;
      #pragma unroll
      for (int jj = 0; jj < 4; ++jj)
        #pragma unroll
        for (int ct = 0; ct < 2; ++ct) {
          float a = acc[rt][ct][4*qq + jj];
          float s = c2v[ct] - 2.f * a;
          dl[(4*half + jj)*512 + w*64 + ct*32 + l31] = vld[ct] ? s : INF;
        }
      __syncthreads();
      const float q2u = q2w[g];
      #pragma unroll
      for (int j2 = 0; j2 < 8; ++j2) {
        float sv = dl[w*512 + l + 64*j2];
        float dv = sqrtf(fmaxf(q2u + sv, 0.f));
        unsigned long long mask = __ballot(dv < wd4[g]);
        while (mask) {
          int L = __ffsll(mask) - 1; mask &= mask - 1;
          float dnew = __shfl(dv, L, 64);
          int ci = cbase + 64*j2 + L;
          if ((dnew < wd4[g]) || (dnew == wd4[g] && ci < wi4[g])) {
            bool isw = (l < 32) && (listd[g] == wd4[g]) && (listi[g] == wi4[g]);
            int wl = __ffsll(__ballot(isw)) - 1;
            if (l == wl) { listd[g] = dnew; listi[g] = ci; }
            worst_reduce((l < 32) ? listd[g] : -1.f,
                         (l < 32) ? listi[g] : -1, wd4[g], wi4[g]);
          }
        }
      }
      __syncthreads();
    }
  }

  #pragma unroll
  for (int g = 0; g < 8; ++g) {
    int gq = mbase + g*8 + w;
    float d = listd[g]; int i = listi[g];
    int rank = 0;
    #pragma unroll
    for (int j = 0; j < KSEL; ++j) {
      float dj = __shfl(listd[g], j, 64);
      int   ij = __shfl(listi[g], j, 64);
      rank += (dj < d) || (dj == d && ij < i);
    }
    if (l < 32 && gq < n1) {
      size_t o = ((size_t)gq * nc + chunkid) * KSEL + rank;
      tkd[o] = d; tki[o] = i;
    }
  }
}

// ---------------- Phase 2: merge + exact rescore + cosine ----------------
__global__ __launch_bounds__(256) void knn_phase2_kernel(
    const float* __restrict__ Q0, const float* __restrict__ Q1,
    const float* __restrict__ C0, const float* __restrict__ C1,
    const float* __restrict__ q2g, const float* __restrict__ c2g,
    const float* __restrict__ tkd, const int* __restrict__ tki,
    float* __restrict__ out, int n1, int n2, int nc)
{
  __shared__ float q0s[D], q1s[D];
  __shared__ float pd[256]; __shared__ int pi[256];
  __shared__ float nd[NSELMX]; __shared__ int ni[NSELMX];
  __shared__ float de[NSELMX];
  __shared__ int   fi[KSEL];
  __shared__ float cosj[KSEL];
  __shared__ float red0[4], red1[4], qn[2];

  const int q = blockIdx.x, tid = threadIdx.x;
  const int npool = nc * KSEL;
  const int nsel  = (NSELMX < npool) ? NSELMX : npool;

  if (tid < 128) ((float4*)q0s)[tid] = ((const float4*)(Q0 + (size_t)q*D))[tid];
  else           ((float4*)q1s)[tid-128] = ((const float4*)(Q1 + (size_t)q*D))[tid-128];
  if (tid < npool) { pd[tid] = tkd[(size_t)q*npool + tid]; pi[tid] = tki[(size_t)q*npool + tid]; }
  __syncthreads();

  float a0 = q0s[tid], b0 = q0s[tid+256], a1 = q1s[tid], b1 = q1s[tid+256];
  float s0 = a0*a0 + b0*b0, s1 = a1*a1 + b1*b1;
  #pragma unroll
  for (int o = 32; o > 0; o >>= 1) { s0 += __shfl_down(s0, o, 64); s1 += __shfl_down(s1, o, 64); }
  int lane = tid & 63, wid = tid >> 6;
  if (lane == 0) { red0[wid] = s0; red1[wid] = s1; }

  if (tid < npool) {
    float dm = pd[tid]; int im = pi[tid]; int rank = 0;
    for (int j = 0; j < npool; ++j) {
      float dj = pd[j]; int ij = pi[j];
      rank += (dj < dm) || (dj == dm && ij < im);
    }
    if (rank < nsel) { nd[rank] = dm; ni[rank] = im; }
  }
  __syncthreads();
  if (tid == 0) {
    qn[0] = fmaxf(sqrtf(red0[0]+red0[1]+red0[2]+red0[3]), CEPS);
    qn[1] = fmaxf(sqrtf(red1[0]+red1[1]+red1[2]+red1[3]), CEPS);
  }

  const float q2q = q2g[q];
  const int ll = tid & 7;
  for (int base = 0; base < NSELMX; base += 32) {
    int g = base + (tid >> 3);
    if (g < nsel) {
      int ix = ni[g];
      bool okx = (ix >= 0 && ix < n2);
      int ixc = okx ? ix : 0;
      const float4* r0  = (const float4*)(C0 + (size_t)ixc * D);
      const float4* q04 = (const float4*)q0s;
      float dot = 0.f;
      #pragma unroll
      for (int r = 0; r < 16; ++r) {
        float4 v = r0[r*8 + ll], u = q04[r*8 + ll];
        dot = fmaf(v.x,u.x, fmaf(v.y,u.y, fmaf(v.z,u.z, fmaf(v.w,u.w, dot))));
      }
      #pragma unroll
      for (int o = 4; o > 0; o >>= 1) dot += __shfl_xor(dot, o, 64);
      if (ll == 0) de[g] = okx ? sqrtf(fmaxf(q2q + c2g[ixc] - 2.f*dot, 0.f)) : INF;
    }
  }
  __syncthreads();

  if (tid < nsel) {
    float dm = de[tid]; int im = ni[tid]; int rank = 0;
    for (int j = 0; j < nsel; ++j) {
      float dj = de[j]; int ij = ni[j];
      rank += (dj < dm) || (dj == dm && ij < im);
    }
    if (rank < KSEL) fi[rank] = im;
  }
  __syncthreads();

  const int g = tid >> 3;
  int ix = fi[g];
  ix = (ix >= 0 && ix < n2) ? ix : 0;
  const float4* r0  = (const float4*)(C0 + (size_t)ix * D);
  const float4* r1  = (const float4*)(C1 + (size_t)ix * D);
  const float4* q04 = (const float4*)q0s;
  const float4* q14 = (const float4*)q1s;
  float dot0 = 0.f, nn0 = 0.f, dot1 = 0.f, nn1 = 0.f;
  #pragma unroll
  for (int r = 0; r < 16; ++r) {
    int e4 = r*8 + ll;
    float4 v0 = r0[e4], qv0 = q04[e4];
    dot0 = fmaf(v0.x,qv0.x, fmaf(v0.y,qv0.y, fmaf(v0.z,qv0.z, fmaf(v0.w,qv0.w, dot0))));
    nn0  = fmaf(v0.x,v0.x,  fmaf(v0.y,v0.y,  fmaf(v0.z,v0.z,  fmaf(v0.w,v0.w,  nn0))));
    float4 v1 = r1[e4], qv1 = q14[e4];
    dot1 = fmaf(v1.x,qv1.x, fmaf(v1.y,qv1.y, fmaf(v1.z,qv1.z, fmaf(v1.w,qv1.w, dot1))));
    nn1  = fmaf(v1.x,v1.x,  fmaf(v1.y,v1.y,  fmaf(v1.z,v1.z,  fmaf(v1.w,v1.w,  nn1))));
  }
  #pragma unroll
  for (int o = 4; o > 0; o >>= 1) {
    dot0 += __shfl_xor(dot0, o, 64); nn0 += __shfl_xor(nn0, o, 64);
    dot1 += __shfl_xor(dot1, o, 64); nn1 += __shfl_xor(nn1, o, 64);
  }
  if (ll == 0) {
    float c0 = dot0 / (fmaxf(sqrtf(nn0), CEPS) * qn[0]);
    float c1 = dot1 / (fmaxf(sqrtf(nn1), CEPS) * qn[1]);
    float cv = (c0 > c1) ? c0 : c1;
    out[(size_t)q * KSEL + g] = cv;
    cosj[g] = cv;
  }
  __syncthreads();
  if (tid == 0) {
    float s = 0.f;
    #pragma unroll
    for (int j = 0; j < KSEL; ++j) s += cosj[j];
    out[(size_t)n1 * KSEL + q] = s * (1.f / KSEL);
  }
}

// ---------------- launch ----------------
extern "C" void kernel_launch(void* const* d_in, const int* in_sizes, int n_in,
                              void* d_out, int out_size, void* d_ws, size_t ws_size,
                              hipStream_t stream)
{
  const float* Q0 = (const float*)d_in[0];
  const float* Q1 = (const float*)d_in[1];
  const float* C0 = (const float*)d_in[2];
  const float* C1 = (const float*)d_in[3];
  const int n1 = in_sizes[0] / D;   // 2048
  const int n2 = in_sizes[2] / D;   // 50000
  float* out = (float*)d_out;
  if (n1 <= 0 || n2 <= 0) return;

  char* wsb = (char*)d_ws;
  size_t c2n = ((size_t)n2 + 127) & ~(size_t)127;
  size_t q2n = ((size_t)n1 + 127) & ~(size_t)127;

  size_t off_c2  = 0;
  size_t off_q2  = off_c2 + c2n*4;
  size_t off_tkd = off_q2 + q2n*4;
  size_t off_tki = off_tkd + (size_t)n1*NCF*KSEL*4;
  size_t off_cb  = (off_tki + (size_t)n1*NCF*KSEL*4 + 255) & ~(size_t)255;
  size_t off_qb  = off_cb + ((size_t)n2 + 512)*D*2;
  size_t need    = off_qb + (size_t)n1*D*2;
  bool fast = (ws_size >= need);

  if (fast) {
    float* c2  = (float*)(wsb + off_c2);
    float* q2  = (float*)(wsb + off_q2);
    float* tkd = (float*)(wsb + off_tkd);
    int*   tki = (int*)(wsb + off_tki);
    unsigned short* Cb = (unsigned short*)(wsb + off_cb);
    unsigned short* Qb = (unsigned short*)(wsb + off_qb);

    int n2e8 = n2 * (D/8), n1e8 = n1 * (D/8);
    precvt_kernel<<<(n2e8 + n1e8 + 255)/256, 256, 0, stream>>>(C0, Q0, Cb, Qb, n2e8, n1e8);
    rows_sumsq_kernel<<<(n2 + n1 + 3)/4, 256, 0, stream>>>(C0, Q0, c2, q2, n2, n1);

    const int chunk  = (n2 + NCF - 1) / NCF;
    const int mtiles = (n1 + MT - 1) / MT;
    (void)hipFuncSetAttribute((const void*)knn_phase1_bf_kernel,
                              hipFuncAttributeMaxDynamicSharedMemorySize, 163840);
    knn_phase1_bf_kernel<<<dim3(mtiles, NCF), NTH, 163840, stream>>>(
        Qb, Cb, q2, c2, tkd, tki, n1, n2, chunk, NCF);
    knn_phase2_kernel<<<n1, 256, 0, stream>>>(Q0, Q1, C0, C1, q2, c2, tkd, tki, out, n1, n2, NCF);
  } else {
    float* wsf = (float*)d_ws;
    int nc = 8;
    while (nc > 1 && (c2n + q2n + (size_t)n1 * nc * KSEL * 2) * 4 > ws_size) nc >>= 1;
    float* c2  = wsf;
    float* q2  = wsf + c2n;
    float* tkd = wsf + c2n + q2n;
    int*   tki = (int*)(wsf + c2n + q2n + (size_t)n1 * nc * KSEL);

    rows_sumsq_kernel<<<(n2 + n1 + 3)/4, 256, 0, stream>>>(C0, Q0, c2, q2, n2, n1);
    const int chunk  = (n2 + nc - 1) / nc;
    const int mtiles = (n1 + MT - 1) / MT;
    (void)hipFuncSetAttribute((const void*)knn_phase1_cvt_kernel,
                              hipFuncAttributeMaxDynamicSharedMemorySize, 163840);
    knn_phase1_cvt_kernel<<<dim3(mtiles, nc), NTH, 163840, stream>>>(
        Q0, C0, q2, c2, tkd, tki, n1, n2, chunk, nc);
    knn_phase2_kernel<<<n1, 256, 0, stream>>>(Q0, Q1, C0, C1, q2, c2, tkd, tki, out, n1, n2, nc);
  }
}

// Round 8
// 518.290 us; speedup vs baseline: 12.5895x; 1.0348x over previous
//
#include <hip/hip_runtime.h>
#include <math.h>

// KNN (L2 top-32) + cosine re-rank, MI355X.
// P0 : fused row sum-of-squares (exact fp32) + fp32->bf16(hi,RTN) table write.
// P1 : 1-pass bf16 MFMA distance GEMM (32x32x16), 64q x 512c tiles, KC=64,
//      global_load_lds DMA staging, double-buffered LDS, counted vmcnt(9).
//      XCD chunk-affinity: chunkid = bid&7 (same-XCD blocks share one chunk ->
//      candidate staging served from per-XCD L2 instead of L3/HBM).
//      Selection: per-lane register top-5 (pure VALU), end-of-chunk
//      pivot+compact+rank -> per-chunk noisy top-32 (d^2 keys).
// P2 : merge 8x32 -> noisy top-64 -> EXACT fp32 rescore -> exact top-32 -> cosine.
// Fallback (small ws): R4's in-kernel-conversion 3-pass kernel (proven).

#define D       512
#define MT      64
#define NT      512
#define KC      64
#define NTH     512
#define KSEL    32
#define NSELMX  64
#define NCF     8      // chunks, fast path (== #XCDs)
#define TOPL    5      // per-lane register list length
#define CEPS    1e-8f
#define INF     __builtin_inff()

using s16x8  = __attribute__((ext_vector_type(8)))  short;
using f32x16 = __attribute__((ext_vector_type(16))) float;

__device__ __forceinline__ void async16(const void* g, void* s) {
  __builtin_amdgcn_global_load_lds(
      (const __attribute__((address_space(1))) unsigned int*)g,
      (__attribute__((address_space(3))) unsigned int*)s, 16, 0, 0);
}

// two fp32 -> packed bf16 pair (RTN)
__device__ __forceinline__ unsigned int bfhi2(float x0, float x1) {
  unsigned int u0 = __float_as_uint(x0), u1 = __float_as_uint(x1);
  u0 = (u0 + 0x7fffu + ((u0 >> 16) & 1u)) >> 16;
  u1 = (u1 + 0x7fffu + ((u1 >> 16) & 1u)) & 0xffff0000u;
  return u0 | u1;
}

// ---------------- P0 (fast): fused sumsq + bf16 conversion ----------------
// one wave per row; lane l owns elements [8l, 8l+8)
__global__ __launch_bounds__(256) void sumsq_cvt_kernel(
    const float* __restrict__ C, const float* __restrict__ Q,
    float* __restrict__ c2, float* __restrict__ q2,
    unsigned short* __restrict__ Cb, unsigned short* __restrict__ Qb,
    int n2, int n1)
{
  int wid  = threadIdx.x >> 6;
  int lane = threadIdx.x & 63;
  int row  = blockIdx.x * 4 + wid;
  const float* src; float* dst; unsigned short* bdst;
  if (row < n2) { src = C + (size_t)row * D; dst = c2 + row; bdst = Cb + (size_t)row * D; }
  else {
    int r = row - n2; if (r >= n1) return;
    src = Q + (size_t)r * D; dst = q2 + r; bdst = Qb + (size_t)r * D;
  }
  const float4* s4 = (const float4*)src;
  float4 a = s4[2*lane], b = s4[2*lane + 1];
  float s = a.x*a.x + a.y*a.y + a.z*a.z + a.w*a.w
          + b.x*b.x + b.y*b.y + b.z*b.z + b.w*b.w;
  int4 h;
  h.x = (int)bfhi2(a.x, a.y); h.y = (int)bfhi2(a.z, a.w);
  h.z = (int)bfhi2(b.x, b.y); h.w = (int)bfhi2(b.z, b.w);
  *(int4*)(bdst + 8*lane) = h;
  #pragma unroll
  for (int o = 32; o > 0; o >>= 1) s += __shfl_down(s, o, 64);
  if (lane == 0) *dst = s;
}

// ---------------- P0 (fallback): row sum-of-squares only ----------------
__global__ __launch_bounds__(256) void rows_sumsq_kernel(
    const float* __restrict__ C, const float* __restrict__ Q,
    float* __restrict__ c2, float* __restrict__ q2, int n2, int n1)
{
  int wid  = threadIdx.x >> 6;
  int lane = threadIdx.x & 63;
  int row  = blockIdx.x * 4 + wid;
  const float* src; float* dst;
  if (row < n2) { src = C + (size_t)row * D; dst = c2 + row; }
  else { int r = row - n2; if (r >= n1) return; src = Q + (size_t)r * D; dst = q2 + r; }
  const float4* s4 = (const float4*)src;
  float4 a = s4[lane], b = s4[lane + 64];
  float s = a.x*a.x + a.y*a.y + a.z*a.z + a.w*a.w
          + b.x*b.x + b.y*b.y + b.z*b.z + b.w*b.w;
  #pragma unroll
  for (int o = 32; o > 0; o >>= 1) s += __shfl_down(s, o, 64);
  if (lane == 0) *dst = s;
}

// lexicographic max of (d,i) over lanes 0..31 (fallback kernel only)
__device__ inline void worst_reduce(float dIn, int iIn, float& wd, int& wi) {
  float dd = dIn; int ii = iIn;
  #pragma unroll
  for (int o = 1; o <= 16; o <<= 1) {
    float dp = __shfl_xor(dd, o, 64);
    int   ip = __shfl_xor(ii, o, 64);
    bool take = (dp > dd) || (dp == dd && ip > ii);
    dd = take ? dp : dd; ii = take ? ip : ii;
  }
  wd = __shfl(dd, 0, 64); wi = __shfl(ii, 0, 64);
}

// fp32 -> (bf16_hi, bf16_lo) split (fallback kernel only)
__device__ inline void cvt8(const float4 a, const float4 b, int4& hi, int4& lo) {
  float x[8] = {a.x, a.y, a.z, a.w, b.x, b.y, b.z, b.w};
  unsigned int hw[8], lw[8];
  #pragma unroll
  for (int j = 0; j < 8; ++j) {
    unsigned int ux = __float_as_uint(x[j]);
    unsigned int rh = (ux + 0x7fffu + ((ux >> 16) & 1u)) & 0xffff0000u;
    float rl = x[j] - __uint_as_float(rh);
    unsigned int ul = __float_as_uint(rl);
    hw[j] = rh >> 16;
    lw[j] = (ul + 0x7fffu + ((ul >> 16) & 1u)) >> 16;
  }
  hi = make_int4((int)(hw[0]|(hw[1]<<16)), (int)(hw[2]|(hw[3]<<16)),
                 (int)(hw[4]|(hw[5]<<16)), (int)(hw[6]|(hw[7]<<16)));
  lo = make_int4((int)(lw[0]|(lw[1]<<16)), (int)(lw[2]|(lw[3]<<16)),
                 (int)(lw[4]|(lw[5]<<16)), (int)(lw[6]|(lw[7]<<16)));
}

// ---------------- Phase 1 (fast): DMA-staged 1-pass bf16 MFMA ----------------
// LDS: qh dbuf 2x8K | ch dbuf 2x64K | dl [8][512] 16K = 160K
// end-of-chunk sel buffer: reuses qh/ch region (dead), 512 u64/wave.
__global__ __launch_bounds__(NTH, 2) void knn_phase1_bf_kernel(
    const unsigned short* __restrict__ Qb, const unsigned short* __restrict__ Cb,
    const float* __restrict__ q2g, const float* __restrict__ c2g,
    float* __restrict__ tkd, int* __restrict__ tki,
    int n1, int n2, int chunk, int nc)
{
  extern __shared__ char smem[];
  unsigned short* qh = (unsigned short*)smem;                // 2 x [64][64]
  unsigned short* ch = qh + 2*64*64;                         // 2 x [512][64]
  float* dl = (float*)(smem + 147456);                       // [8][512]

  const int tid  = threadIdx.x;
  const int w    = tid >> 6;
  const int l    = tid & 63;
  const int l31  = l & 31;
  const int half = l >> 5;
  // XCD chunk-affinity: hardware XCD ~ blockIdx % 8; give each XCD one chunk
  const int bid     = blockIdx.x;
  const int chunkid = bid & (NCF - 1);
  const int mbase   = (bid >> 3) * MT;
  const int cbase0  = chunkid * chunk;
  const int cend    = min(cbase0 + chunk, n2);

  float q2w[8];
  #pragma unroll
  for (int g = 0; g < 8; ++g) q2w[g] = q2g[min(mbase + g*8 + w, n1 - 1)];

  // per-lane register top-TOPL lists, one per owned row (row g*8+w), sorted asc
  unsigned long long vv[8][TOPL];
  #pragma unroll
  for (int g = 0; g < 8; ++g)
    #pragma unroll
    for (int t = 0; t < TOPL; ++t) vv[g][t] = 0xffffffffffffffffULL;

  const int lrow = l >> 3;                 // row-within-8 of this lane
  const int su   = (l & 7) ^ lrow;         // pre-swizzled source unit

  auto STAGE = [&](int buf, int kb, int cb) {
    {
      int gm = min(mbase + w*8 + lrow, n1 - 1);
      const unsigned short* src = Qb + (size_t)gm * D + kb*KC + su*8;
      unsigned short* dst = qh + buf*(64*64) + (w*8)*64;     // wave-uniform base
      async16(src, dst);
    }
    #pragma unroll
    for (int i = 0; i < 8; ++i) {
      int gn = cb + w*64 + i*8 + lrow;                       // may overrun cend (padded)
      const unsigned short* src = Cb + (size_t)gn * D + kb*KC + su*8;
      unsigned short* dst = ch + buf*(512*64) + (w*64 + i*8)*64;
      async16(src, dst);
    }
  };

  f32x16 zf;
  #pragma unroll
  for (int e = 0; e < 16; ++e) zf[e] = 0.f;

  const int nsteps = (cend - cbase0 + NT - 1) / NT;
  int b = 0;
  STAGE(0, 0, cbase0);
  __syncthreads();            // drain prologue

  for (int nt = 0; nt < nsteps; ++nt) {
    const int cbase = cbase0 + nt * NT;
    f32x16 acc[2][2];
    #pragma unroll
    for (int rt = 0; rt < 2; ++rt)
      #pragma unroll
      for (int ct = 0; ct < 2; ++ct) acc[rt][ct] = zf;

    for (int kb = 0; kb < D/KC; ++kb) {
      if (kb + 1 < D/KC) {
        STAGE(b^1, kb+1, cbase);
        asm volatile("s_waitcnt vmcnt(9)" ::: "memory");
      } else if (nt + 1 < nsteps) {
        STAGE(b^1, 0, cbase + NT);
        asm volatile("s_waitcnt vmcnt(9)" ::: "memory");
      } else {
        asm volatile("s_waitcnt vmcnt(0)" ::: "memory");
      }
      __builtin_amdgcn_s_barrier();
      __builtin_amdgcn_sched_barrier(0);

      const unsigned short* qb  = qh + b*(64*64);
      const unsigned short* cbf = ch + b*(512*64);
      #pragma unroll
      for (int ks = 0; ks < 4; ++ks) {
        const int u = 2*ks + half;
        s16x8 qf[2], cf[2];
        #pragma unroll
        for (int rt = 0; rt < 2; ++rt) {
          int r = rt*32 + l31;
          qf[rt] = *(const s16x8*)(qb + r*64 + (u ^ (r & 7))*8);
        }
        #pragma unroll
        for (int ct = 0; ct < 2; ++ct) {
          int c = w*64 + ct*32 + l31;
          cf[ct] = *(const s16x8*)(cbf + c*64 + (u ^ (c & 7))*8);
        }
        #pragma unroll
        for (int rt = 0; rt < 2; ++rt)
          #pragma unroll
          for (int ct = 0; ct < 2; ++ct)
            acc[rt][ct] = __builtin_amdgcn_mfma_f32_32x32x16_bf16(qf[rt], cf[ct], acc[rt][ct], 0, 0, 0);
      }
      asm volatile("s_waitcnt lgkmcnt(0)" ::: "memory");
      __builtin_amdgcn_s_barrier();
      __builtin_amdgcn_sched_barrier(0);
      b ^= 1;
    }

    // epilogue: s = c2 - 2*dot -> dl (8-row groups); per-lane register filter
    float c2v[2]; int vld[2];
    #pragma unroll
    for (int ct = 0; ct < 2; ++ct) {
      int gc = cbase + w*64 + ct*32 + l31;
      vld[ct] = (gc < cend);
      c2v[ct] = vld[ct] ? c2g[gc] : 0.f;
    }
    #pragma unroll
    for (int g = 0; g < 8; ++g) {
      const int rt = g >> 2, qq = g & 3;
      #pragma unroll
      for (int jj = 0; jj < 4; ++jj)
        #pragma unroll
        for (int ct = 0; ct < 2; ++ct) {
          float a = acc[rt][ct][4*qq + jj];
          float s = c2v[ct] - 2.f * a;
          dl[(4*half + jj)*512 + w*64 + ct*32 + l31] = vld[ct] ? s : INF;
        }
      __syncthreads();
      // wave w filters row g*8+w: pure-VALU per-lane top-TOPL insert
      const float q2u = q2w[g];
      #pragma unroll
      for (int j2 = 0; j2 < 8; ++j2) {
        float sv  = dl[w*512 + l + 64*j2];
        float d2v = fmaxf(q2u + sv, 0.f);            // INF stays INF
        unsigned int kbit = __float_as_uint(d2v);
        unsigned int ci = (kbit != 0x7f800000u) ? (unsigned)(cbase + 64*j2 + l)
                                                : 0x7fffffffu;
        unsigned long long e = ((unsigned long long)kbit << 32) | ci;
        if (e < vv[g][TOPL-1]) {
          vv[g][TOPL-1] = e;
          #pragma unroll
          for (int t = TOPL-1; t > 0; --t) {
            unsigned long long lo = vv[g][t-1] < vv[g][t] ? vv[g][t-1] : vv[g][t];
            unsigned long long hi = vv[g][t-1] < vv[g][t] ? vv[g][t]   : vv[g][t-1];
            vv[g][t-1] = lo; vv[g][t] = hi;
          }
        }
      }
      __syncthreads();
    }
  }

  // ---- end-of-chunk selection: pivot + compact + rank (per wave) ----
  // sel lives in the dead qh/ch region: 512 u64 per wave (max Ns = 320).
  unsigned long long* sel = (unsigned long long*)smem + (size_t)w * 512;
  const unsigned long long mlt = (l == 0) ? 0ull : ((~0ull) >> (64 - l)); // lanes < me
  __syncthreads();   // everyone past the main loop before qh/ch reuse
  #pragma unroll
  for (int g = 0; g < 8; ++g) {
    // pivot key = max over lanes of key(vv[g][0]); guarantees >=64 survivors
    unsigned int pk = (unsigned int)(vv[g][0] >> 32);
    #pragma unroll
    for (int o = 1; o < 64; o <<= 1) {
      unsigned int other = (unsigned int)__shfl_xor((int)pk, o, 64);
      pk = (other > pk) ? other : pk;
    }
    int cnt = 0;
    #pragma unroll
    for (int t = 0; t < TOPL; ++t) cnt += ((unsigned int)(vv[g][t] >> 32) <= pk) ? 1 : 0;
    unsigned long long b0 = __ballot(cnt & 1);
    unsigned long long b1 = __ballot(cnt & 2);
    unsigned long long b2 = __ballot(cnt & 4);
    int pre = __popcll(b0 & mlt) + 2*__popcll(b1 & mlt) + 4*__popcll(b2 & mlt);
    int Ns  = __popcll(b0) + 2*__popcll(b1) + 4*__popcll(b2);
    #pragma unroll
    for (int t = 0; t < TOPL; ++t)
      if (t < cnt) sel[pre + t] = vv[g][t];
    asm volatile("s_waitcnt lgkmcnt(0)" ::: "memory");
    __builtin_amdgcn_sched_barrier(0);
    int rk[TOPL];
    #pragma unroll
    for (int t = 0; t < TOPL; ++t) rk[t] = 0;
    for (int j = 0; j < Ns; ++j) {
      unsigned long long e = sel[j];
      #pragma unroll
      for (int t = 0; t < TOPL; ++t) rk[t] += (e < vv[g][t]) ? 1 : 0;
    }
    int gq = mbase + g*8 + w;
    if (gq < n1) {
      #pragma unroll
      for (int t = 0; t < TOPL; ++t)
        if (t < cnt && rk[t] < KSEL) {
          size_t o = ((size_t)gq * nc + chunkid) * KSEL + rk[t];
          tkd[o] = __uint_as_float((unsigned int)(vv[g][t] >> 32));
          tki[o] = (int)(unsigned int)(vv[g][t] & 0xffffffffu);
        }
    }
  }
}

// ---------------- Phase 1 (fallback): R4 in-kernel-conversion 3-pass ----------------
__global__ __launch_bounds__(NTH) void knn_phase1_cvt_kernel(
    const float* __restrict__ Q, const float* __restrict__ C,
    const float* __restrict__ q2g, const float* __restrict__ c2g,
    float* __restrict__ tkd, int* __restrict__ tki,
    int n1, int n2, int chunk, int nc)
{
  extern __shared__ char smem[];
  unsigned short* qh = (unsigned short*)smem;
  unsigned short* ql = qh + 64*64;
  unsigned short* ch = ql + 64*64;
  unsigned short* cl = ch + 512*64;
  float* dl = (float*)(smem + 147456);

  const int tid  = threadIdx.x;
  const int w    = tid >> 6;
  const int l    = tid & 63;
  const int l31  = l & 31;
  const int half = l >> 5;
  const int mbase   = blockIdx.x * MT;
  const int chunkid = blockIdx.y;
  const int cbase0  = chunkid * chunk;
  const int cend    = min(cbase0 + chunk, n2);

  float q2w[8];
  #pragma unroll
  for (int g = 0; g < 8; ++g) q2w[g] = q2g[min(mbase + g*8 + w, n1 - 1)];

  float listd[8]; int listi[8]; float wd4[8]; int wi4[8];
  #pragma unroll
  for (int g = 0; g < 8; ++g) { listd[g]=INF; listi[g]=0x7fffffff; wd4[g]=INF; wi4[g]=0x7fffffff; }

  const int srow = tid >> 3;
  const int sk8  = (tid & 7) * 8;
  const int su   = (tid & 7);

  float4 cva[8][2], qva[2];
  auto LOADR = [&](int kb, int cb) {
    {
      int gr = min(mbase + srow, n1 - 1);
      const float4* p = (const float4*)(Q + (size_t)gr * D + kb*KC + sk8);
      qva[0] = p[0]; qva[1] = p[1];
    }
    #pragma unroll
    for (int r = 0; r < 8; ++r) {
      int gn = cb + srow + 64*r;
      if (gn < cend) {
        const float4* p = (const float4*)(C + (size_t)gn * D + kb*KC + sk8);
        cva[r][0] = p[0]; cva[r][1] = p[1];
      } else {
        cva[r][0] = make_float4(0.f,0.f,0.f,0.f);
        cva[r][1] = make_float4(0.f,0.f,0.f,0.f);
      }
    }
  };
  auto STORE = [&]() {
    int4 hi, lo;
    {
      int idx = srow*64 + (su ^ (srow & 7))*8;
      cvt8(qva[0], qva[1], hi, lo);
      *(int4*)(qh + idx) = hi; *(int4*)(ql + idx) = lo;
    }
    #pragma unroll
    for (int r = 0; r < 8; ++r) {
      int row = srow + 64*r;
      int idx = row*64 + (su ^ (row & 7))*8;
      cvt8(cva[r][0], cva[r][1], hi, lo);
      *(int4*)(ch + idx) = hi; *(int4*)(cl + idx) = lo;
    }
  };

  f32x16 zf;
  #pragma unroll
  for (int e = 0; e < 16; ++e) zf[e] = 0.f;

  const int nsteps = (cend - cbase0 + NT - 1) / NT;
  LOADR(0, cbase0);

  for (int nt = 0; nt < nsteps; ++nt) {
    const int cbase = cbase0 + nt * NT;
    f32x16 acc[2][2];
    #pragma unroll
    for (int rt = 0; rt < 2; ++rt)
      #pragma unroll
      for (int ct = 0; ct < 2; ++ct) acc[rt][ct] = zf;

    for (int kb = 0; kb < D/KC; ++kb) {
      __syncthreads();
      STORE();
      __syncthreads();
      if (kb + 1 < D/KC)        LOADR(kb + 1, cbase);
      else if (nt + 1 < nsteps) LOADR(0, cbase + NT);

      #pragma unroll
      for (int ks = 0; ks < 4; ++ks) {
        const int u = 2*ks + half;
        s16x8 qf[2][2], cf[2][2];
        #pragma unroll
        for (int rt = 0; rt < 2; ++rt) {
          int r = rt*32 + l31;
          int idx = r*64 + (u ^ (r & 7))*8;
          qf[rt][0] = *(const s16x8*)(qh + idx);
          qf[rt][1] = *(const s16x8*)(ql + idx);
        }
        #pragma unroll
        for (int ct = 0; ct < 2; ++ct) {
          int c = w*64 + ct*32 + l31;
          int idx = c*64 + (u ^ (c & 7))*8;
          cf[ct][0] = *(const s16x8*)(ch + idx);
          cf[ct][1] = *(const s16x8*)(cl + idx);
        }
        #pragma unroll
        for (int rt = 0; rt < 2; ++rt)
          #pragma unroll
          for (int ct = 0; ct < 2; ++ct) {
            acc[rt][ct] = __builtin_amdgcn_mfma_f32_32x32x16_bf16(qf[rt][0], cf[ct][0], acc[rt][ct], 0, 0, 0);
            acc[rt][ct] = __builtin_amdgcn_mfma_f32_32x32x16_bf16(qf[rt][0], cf[ct][1], acc[rt][ct], 0, 0, 0);
            acc[rt][ct] = __builtin_amdgcn_mfma_f32_32x32x16_bf16(qf[rt][1], cf[ct][0], acc[rt][ct], 0, 0, 0);
          }
      }
    }

    float c2v[2]; int vld[2];
    #pragma unroll
    for (int ct = 0; ct < 2; ++ct) {
      int gc = cbase + w*64 + ct*32 + l31;
      vld[ct] = (gc < cend);
      c2v[ct] = vld[ct] ? c2g[gc] : 0.f;
    }
    #pragma unroll
    for (int g = 0; g < 8; ++g) {
      const int rt = g >> 2, qq = g & 3;
      #pragma unroll
      for (int jj = 0; jj < 4; ++jj)
        #pragma unroll
        for (int ct = 0; ct < 2; ++ct) {
          float a = acc[rt][ct][4*qq + jj];
          float s = c2v[ct] - 2.f * a;
          dl[(4*half + jj)*512 + w*64 + ct*32 + l31] = vld[ct] ? s : INF;
        }
      __syncthreads();
      const float q2u = q2w[g];
      #pragma unroll
      for (int j2 = 0; j2 < 8; ++j2) {
        float sv = dl[w*512 + l + 64*j2];
        float dv = sqrtf(fmaxf(q2u + sv, 0.f));
        unsigned long long mask = __ballot(dv < wd4[g]);
        while (mask) {
          int L = __ffsll(mask) - 1; mask &= mask - 1;
          float dnew = __shfl(dv, L, 64);
          int ci = cbase + 64*j2 + L;
          if ((dnew < wd4[g]) || (dnew == wd4[g] && ci < wi4[g])) {
            bool isw = (l < 32) && (listd[g] == wd4[g]) && (listi[g] == wi4[g]);
            int wl = __ffsll(__ballot(isw)) - 1;
            if (l == wl) { listd[g] = dnew; listi[g] = ci; }
            worst_reduce((l < 32) ? listd[g] : -1.f,
                         (l < 32) ? listi[g] : -1, wd4[g], wi4[g]);
          }
        }
      }
      __syncthreads();
    }
  }

  #pragma unroll
  for (int g = 0; g < 8; ++g) {
    int gq = mbase + g*8 + w;
    float d = listd[g]; int i = listi[g];
    int rank = 0;
    #pragma unroll
    for (int j = 0; j < KSEL; ++j) {
      float dj = __shfl(listd[g], j, 64);
      int   ij = __shfl(listi[g], j, 64);
      rank += (dj < d) || (dj == d && ij < i);
    }
    if (l < 32 && gq < n1) {
      size_t o = ((size_t)gq * nc + chunkid) * KSEL + rank;
      tkd[o] = d; tki[o] = i;
    }
  }
}

// ---------------- Phase 2: merge + exact rescore + cosine ----------------
__global__ __launch_bounds__(256) void knn_phase2_kernel(
    const float* __restrict__ Q0, const float* __restrict__ Q1,
    const float* __restrict__ C0, const float* __restrict__ C1,
    const float* __restrict__ q2g, const float* __restrict__ c2g,
    const float* __restrict__ tkd, const int* __restrict__ tki,
    float* __restrict__ out, int n1, int n2, int nc)
{
  __shared__ float q0s[D], q1s[D];
  __shared__ float pd[256]; __shared__ int pi[256];
  __shared__ float nd[NSELMX]; __shared__ int ni[NSELMX];
  __shared__ float de[NSELMX];
  __shared__ int   fi[KSEL];
  __shared__ float cosj[KSEL];
  __shared__ float red0[4], red1[4], qn[2];

  const int q = blockIdx.x, tid = threadIdx.x;
  const int npool = nc * KSEL;
  const int nsel  = (NSELMX < npool) ? NSELMX : npool;

  if (tid < 128) ((float4*)q0s)[tid] = ((const float4*)(Q0 + (size_t)q*D))[tid];
  else           ((float4*)q1s)[tid-128] = ((const float4*)(Q1 + (size_t)q*D))[tid-128];
  if (tid < npool) { pd[tid] = tkd[(size_t)q*npool + tid]; pi[tid] = tki[(size_t)q*npool + tid]; }
  __syncthreads();

  float a0 = q0s[tid], b0 = q0s[tid+256], a1 = q1s[tid], b1 = q1s[tid+256];
  float s0 = a0*a0 + b0*b0, s1 = a1*a1 + b1*b1;
  #pragma unroll
  for (int o = 32; o > 0; o >>= 1) { s0 += __shfl_down(s0, o, 64); s1 += __shfl_down(s1, o, 64); }
  int lane = tid & 63, wid = tid >> 6;
  if (lane == 0) { red0[wid] = s0; red1[wid] = s1; }

  if (tid < npool) {
    float dm = pd[tid]; int im = pi[tid]; int rank = 0;
    for (int j = 0; j < npool; ++j) {
      float dj = pd[j]; int ij = pi[j];
      rank += (dj < dm) || (dj == dm && ij < im);
    }
    if (rank < nsel) { nd[rank] = dm; ni[rank] = im; }
  }
  __syncthreads();
  if (tid == 0) {
    qn[0] = fmaxf(sqrtf(red0[0]+red0[1]+red0[2]+red0[3]), CEPS);
    qn[1] = fmaxf(sqrtf(red1[0]+red1[1]+red1[2]+red1[3]), CEPS);
  }

  const float q2q = q2g[q];
  const int ll = tid & 7;
  for (int base = 0; base < NSELMX; base += 32) {
    int g = base + (tid >> 3);
    if (g < nsel) {
      int ix = ni[g];
      bool okx = (ix >= 0 && ix < n2);
      int ixc = okx ? ix : 0;
      const float4* r0  = (const float4*)(C0 + (size_t)ixc * D);
      const float4* q04 = (const float4*)q0s;
      float dot = 0.f;
      #pragma unroll
      for (int r = 0; r < 16; ++r) {
        float4 v = r0[r*8 + ll], u = q04[r*8 + ll];
        dot = fmaf(v.x,u.x, fmaf(v.y,u.y, fmaf(v.z,u.z, fmaf(v.w,u.w, dot))));
      }
      #pragma unroll
      for (int o = 4; o > 0; o >>= 1) dot += __shfl_xor(dot, o, 64);
      if (ll == 0) de[g] = okx ? sqrtf(fmaxf(q2q + c2g[ixc] - 2.f*dot, 0.f)) : INF;
    }
  }
  __syncthreads();

  if (tid < nsel) {
    float dm = de[tid]; int im = ni[tid]; int rank = 0;
    for (int j = 0; j < nsel; ++j) {
      float dj = de[j]; int ij = ni[j];
      rank += (dj < dm) || (dj == dm && ij < im);
    }
    if (rank < KSEL) fi[rank] = im;
  }
  __syncthreads();

  const int g = tid >> 3;
  int ix = fi[g];
  ix = (ix >= 0 && ix < n2) ? ix : 0;
  const float4* r0  = (const float4*)(C0 + (size_t)ix * D);
  const float4* r1  = (const float4*)(C1 + (size_t)ix * D);
  const float4* q04 = (const float4*)q0s;
  const float4* q14 = (const float4*)q1s;
  float dot0 = 0.f, nn0 = 0.f, dot1 = 0.f, nn1 = 0.f;
  #pragma unroll
  for (int r = 0; r < 16; ++r) {
    int e4 = r*8 + ll;
    float4 v0 = r0[e4], qv0 = q04[e4];
    dot0 = fmaf(v0.x,qv0.x, fmaf(v0.y,qv0.y, fmaf(v0.z,qv0.z, fmaf(v0.w,qv0.w, dot0))));
    nn0  = fmaf(v0.x,v0.x,  fmaf(v0.y,v0.y,  fmaf(v0.z,v0.z,  fmaf(v0.w,v0.w,  nn0))));
    float4 v1 = r1[e4], qv1 = q14[e4];
    dot1 = fmaf(v1.x,qv1.x, fmaf(v1.y,qv1.y, fmaf(v1.z,qv1.z, fmaf(v1.w,qv1.w, dot1))));
    nn1  = fmaf(v1.x,v1.x,  fmaf(v1.y,v1.y,  fmaf(v1.z,v1.z,  fmaf(v1.w,v1.w,  nn1))));
  }
  #pragma unroll
  for (int o = 4; o > 0; o >>= 1) {
    dot0 += __shfl_xor(dot0, o, 64); nn0 += __shfl_xor(nn0, o, 64);
    dot1 += __shfl_xor(dot1, o, 64); nn1 += __shfl_xor(nn1, o, 64);
  }
  if (ll == 0) {
    float c0 = dot0 / (fmaxf(sqrtf(nn0), CEPS) * qn[0]);
    float c1 = dot1 / (fmaxf(sqrtf(nn1), CEPS) * qn[1]);
    float cv = (c0 > c1) ? c0 : c1;
    out[(size_t)q * KSEL + g] = cv;
    cosj[g] = cv;
  }
  __syncthreads();
  if (tid == 0) {
    float s = 0.f;
    #pragma unroll
    for (int j = 0; j < KSEL; ++j) s += cosj[j];
    out[(size_t)n1 * KSEL + q] = s * (1.f / KSEL);
  }
}

// ---------------- launch ----------------
extern "C" void kernel_launch(void* const* d_in, const int* in_sizes, int n_in,
                              void* d_out, int out_size, void* d_ws, size_t ws_size,
                              hipStream_t stream)
{
  const float* Q0 = (const float*)d_in[0];
  const float* Q1 = (const float*)d_in[1];
  const float* C0 = (const float*)d_in[2];
  const float* C1 = (const float*)d_in[3];
  const int n1 = in_sizes[0] / D;   // 2048
  const int n2 = in_sizes[2] / D;   // 50000
  float* out = (float*)d_out;
  if (n1 <= 0 || n2 <= 0) return;

  char* wsb = (char*)d_ws;
  size_t c2n = ((size_t)n2 + 127) & ~(size_t)127;
  size_t q2n = ((size_t)n1 + 127) & ~(size_t)127;

  size_t off_c2  = 0;
  size_t off_q2  = off_c2 + c2n*4;
  size_t off_tkd = off_q2 + q2n*4;
  size_t off_tki = off_tkd + (size_t)n1*NCF*KSEL*4;
  size_t off_cb  = (off_tki + (size_t)n1*NCF*KSEL*4 + 255) & ~(size_t)255;
  size_t off_qb  = off_cb + ((size_t)n2 + 512)*D*2;
  size_t need    = off_qb + (size_t)n1*D*2;
  bool fast = (ws_size >= need);

  if (fast) {
    float* c2  = (float*)(wsb + off_c2);
    float* q2  = (float*)(wsb + off_q2);
    float* tkd = (float*)(wsb + off_tkd);
    int*   tki = (int*)(wsb + off_tki);
    unsigned short* Cb = (unsigned short*)(wsb + off_cb);
    unsigned short* Qb = (unsigned short*)(wsb + off_qb);

    sumsq_cvt_kernel<<<(n2 + n1 + 3)/4, 256, 0, stream>>>(C0, Q0, c2, q2, Cb, Qb, n2, n1);

    const int chunk  = (n2 + NCF - 1) / NCF;
    const int mtiles = (n1 + MT - 1) / MT;
    (void)hipFuncSetAttribute((const void*)knn_phase1_bf_kernel,
                              hipFuncAttributeMaxDynamicSharedMemorySize, 163840);
    knn_phase1_bf_kernel<<<mtiles * NCF, NTH, 163840, stream>>>(
        Qb, Cb, q2, c2, tkd, tki, n1, n2, chunk, NCF);
    knn_phase2_kernel<<<n1, 256, 0, stream>>>(Q0, Q1, C0, C1, q2, c2, tkd, tki, out, n1, n2, NCF);
  } else {
    float* wsf = (float*)d_ws;
    int nc = 8;
    while (nc > 1 && (c2n + q2n + (size_t)n1 * nc * KSEL * 2) * 4 > ws_size) nc >>= 1;
    float* c2  = wsf;
    float* q2  = wsf + c2n;
    float* tkd = wsf + c2n + q2n;
    int*   tki = (int*)(wsf + c2n + q2n + (size_t)n1 * nc * KSEL);

    rows_sumsq_kernel<<<(n2 + n1 + 3)/4, 256, 0, stream>>>(C0, Q0, c2, q2, n2, n1);
    const int chunk  = (n2 + nc - 1) / nc;
    const int mtiles = (n1 + MT - 1) / MT;
    (void)hipFuncSetAttribute((const void*)knn_phase1_cvt_kernel,
                              hipFuncAttributeMaxDynamicSharedMemorySize, 163840);
    knn_phase1_cvt_kernel<<<dim3(mtiles, nc), NTH, 163840, stream>>>(
        Q0, C0, q2, c2, tkd, tki, n1, n2, chunk, nc);
    knn_phase2_kernel<<<n1, 256, 0, stream>>>(Q0, Q1, C0, C1, q2, c2, tkd, tki, out, n1, n2, nc);
  }
}

// Round 9
// 479.679 us; speedup vs baseline: 13.6028x; 1.0805x over previous
//
#include <hip/hip_runtime.h>
#include <math.h>

// KNN (L2 top-32) + cosine re-rank, MI355X.
// P0 : fused row sum-of-squares (exact fp32) + fp32->bf16(hi,RTN) table write.
// P1 : 1-pass bf16 MFMA distance GEMM (32x32x16), 32q x 256c tiles, KC=64,
//      256 threads (4 waves), 80KB LDS -> 2 INDEPENDENT blocks/CU (the two
//      blocks hide each other's barrier/vmcnt/epilogue stalls).
//      global_load_lds DMA staging, double-buffered LDS, counted vmcnt(9).
//      XCD chunk-affinity: chunkid = bid&7.
//      Selection: per-lane register top-5 (pure VALU), end-of-chunk
//      pivot+compact+rank -> per-chunk noisy top-32 (d^2 keys).
// P2 : merge 8x32 -> noisy top-64 -> EXACT fp32 rescore -> exact top-32 -> cosine.
// Fallback (small ws): R4's in-kernel-conversion 3-pass kernel (proven).

#define D       512
#define KSEL    32
#define NSELMX  64
#define NCF     8      // chunks == #XCDs
#define TOPL    5
#define CEPS    1e-8f
#define INF     __builtin_inff()

// fast-path phase-1 geometry
#define MTF     32
#define NTF     256
#define KCF     64
#define NTHF    256

// fallback geometry (R4 kernel, unchanged)
#define MT      64
#define NT      512
#define KC      64
#define NTH     512

using s16x8  = __attribute__((ext_vector_type(8)))  short;
using f32x16 = __attribute__((ext_vector_type(16))) float;

__device__ __forceinline__ void async16(const void* g, void* s) {
  __builtin_amdgcn_global_load_lds(
      (const __attribute__((address_space(1))) unsigned int*)g,
      (__attribute__((address_space(3))) unsigned int*)s, 16, 0, 0);
}

// two fp32 -> packed bf16 pair (RTN)
__device__ __forceinline__ unsigned int bfhi2(float x0, float x1) {
  unsigned int u0 = __float_as_uint(x0), u1 = __float_as_uint(x1);
  u0 = (u0 + 0x7fffu + ((u0 >> 16) & 1u)) >> 16;
  u1 = (u1 + 0x7fffu + ((u1 >> 16) & 1u)) & 0xffff0000u;
  return u0 | u1;
}

// ---------------- P0 (fast): fused sumsq + bf16 conversion ----------------
__global__ __launch_bounds__(256) void sumsq_cvt_kernel(
    const float* __restrict__ C, const float* __restrict__ Q,
    float* __restrict__ c2, float* __restrict__ q2,
    unsigned short* __restrict__ Cb, unsigned short* __restrict__ Qb,
    int n2, int n1)
{
  int wid  = threadIdx.x >> 6;
  int lane = threadIdx.x & 63;
  int row  = blockIdx.x * 4 + wid;
  const float* src; float* dst; unsigned short* bdst;
  if (row < n2) { src = C + (size_t)row * D; dst = c2 + row; bdst = Cb + (size_t)row * D; }
  else {
    int r = row - n2; if (r >= n1) return;
    src = Q + (size_t)r * D; dst = q2 + r; bdst = Qb + (size_t)r * D;
  }
  const float4* s4 = (const float4*)src;
  float4 a = s4[2*lane], b = s4[2*lane + 1];
  float s = a.x*a.x + a.y*a.y + a.z*a.z + a.w*a.w
          + b.x*b.x + b.y*b.y + b.z*b.z + b.w*b.w;
  int4 h;
  h.x = (int)bfhi2(a.x, a.y); h.y = (int)bfhi2(a.z, a.w);
  h.z = (int)bfhi2(b.x, b.y); h.w = (int)bfhi2(b.z, b.w);
  *(int4*)(bdst + 8*lane) = h;
  #pragma unroll
  for (int o = 32; o > 0; o >>= 1) s += __shfl_down(s, o, 64);
  if (lane == 0) *dst = s;
}

// ---------------- P0 (fallback): row sum-of-squares only ----------------
__global__ __launch_bounds__(256) void rows_sumsq_kernel(
    const float* __restrict__ C, const float* __restrict__ Q,
    float* __restrict__ c2, float* __restrict__ q2, int n2, int n1)
{
  int wid  = threadIdx.x >> 6;
  int lane = threadIdx.x & 63;
  int row  = blockIdx.x * 4 + wid;
  const float* src; float* dst;
  if (row < n2) { src = C + (size_t)row * D; dst = c2 + row; }
  else { int r = row - n2; if (r >= n1) return; src = Q + (size_t)r * D; dst = q2 + r; }
  const float4* s4 = (const float4*)src;
  float4 a = s4[lane], b = s4[lane + 64];
  float s = a.x*a.x + a.y*a.y + a.z*a.z + a.w*a.w
          + b.x*b.x + b.y*b.y + b.z*b.z + b.w*b.w;
  #pragma unroll
  for (int o = 32; o > 0; o >>= 1) s += __shfl_down(s, o, 64);
  if (lane == 0) *dst = s;
}

// lexicographic max of (d,i) over lanes 0..31 (fallback kernel only)
__device__ inline void worst_reduce(float dIn, int iIn, float& wd, int& wi) {
  float dd = dIn; int ii = iIn;
  #pragma unroll
  for (int o = 1; o <= 16; o <<= 1) {
    float dp = __shfl_xor(dd, o, 64);
    int   ip = __shfl_xor(ii, o, 64);
    bool take = (dp > dd) || (dp == dd && ip > ii);
    dd = take ? dp : dd; ii = take ? ip : ii;
  }
  wd = __shfl(dd, 0, 64); wi = __shfl(ii, 0, 64);
}

// fp32 -> (bf16_hi, bf16_lo) split (fallback kernel only)
__device__ inline void cvt8(const float4 a, const float4 b, int4& hi, int4& lo) {
  float x[8] = {a.x, a.y, a.z, a.w, b.x, b.y, b.z, b.w};
  unsigned int hw[8], lw[8];
  #pragma unroll
  for (int j = 0; j < 8; ++j) {
    unsigned int ux = __float_as_uint(x[j]);
    unsigned int rh = (ux + 0x7fffu + ((ux >> 16) & 1u)) & 0xffff0000u;
    float rl = x[j] - __uint_as_float(rh);
    unsigned int ul = __float_as_uint(rl);
    hw[j] = rh >> 16;
    lw[j] = (ul + 0x7fffu + ((ul >> 16) & 1u)) >> 16;
  }
  hi = make_int4((int)(hw[0]|(hw[1]<<16)), (int)(hw[2]|(hw[3]<<16)),
                 (int)(hw[4]|(hw[5]<<16)), (int)(hw[6]|(hw[7]<<16)));
  lo = make_int4((int)(lw[0]|(lw[1]<<16)), (int)(lw[2]|(lw[3]<<16)),
                 (int)(lw[4]|(lw[5]<<16)), (int)(lw[6]|(lw[7]<<16)));
}

// ---------------- Phase 1 (fast): 2-blocks/CU DMA-staged bf16 MFMA ----------------
// LDS (80KB): qh dbuf 2x4K [0,8K) | ch dbuf 2x32K [8K,72K) | dl [8][256] 8K [72K,80K)
// end-of-chunk sel buffer reuses [0,64K): 2048 u64/wave (max survivors 320).
__global__ __launch_bounds__(NTHF, 2) void knn_phase1_bf_kernel(
    const unsigned short* __restrict__ Qb, const unsigned short* __restrict__ Cb,
    const float* __restrict__ q2g, const float* __restrict__ c2g,
    float* __restrict__ tkd, int* __restrict__ tki,
    int n1, int n2, int chunk, int nc)
{
  extern __shared__ char smem[];
  unsigned short* qh = (unsigned short*)smem;                // 2 x [32][64]
  unsigned short* ch = (unsigned short*)(smem + 8192);       // 2 x [256][64]
  float* dl = (float*)(smem + 73728);                        // [8][256]

  const int tid  = threadIdx.x;
  const int w    = tid >> 6;       // wave 0..3
  const int l    = tid & 63;
  const int l31  = l & 31;
  const int half = l >> 5;
  // XCD chunk-affinity: hardware XCD ~ blockIdx % 8
  const int bid     = blockIdx.x;
  const int chunkid = bid & (NCF - 1);
  const int mbase   = (bid >> 3) * MTF;
  const int cbase0  = chunkid * chunk;
  const int cend    = min(cbase0 + chunk, n2);

  // list g (g=0..7) = local row 8*(g>>1) + 2*w + (g&1)
  float q2w[8];
  #pragma unroll
  for (int g = 0; g < 8; ++g)
    q2w[g] = q2g[min(mbase + 8*(g>>1) + 2*w + (g&1), n1 - 1)];

  unsigned long long vv[8][TOPL];
  #pragma unroll
  for (int g = 0; g < 8; ++g)
    #pragma unroll
    for (int t = 0; t < TOPL; ++t) vv[g][t] = 0xffffffffffffffffULL;

  const int lrow = l >> 3;                 // row-within-8 of this lane
  const int su   = (l & 7) ^ lrow;         // pre-swizzled source unit

  // 9 x global_load_lds per thread (1 Q + 8 C)
  auto STAGE = [&](int buf, int kb, int cb) {
    {
      int gm = min(mbase + w*8 + lrow, n1 - 1);
      const unsigned short* src = Qb + (size_t)gm * D + kb*KCF + su*8;
      unsigned short* dst = qh + buf*(32*64) + (w*8)*64;     // wave-uniform base
      async16(src, dst);
    }
    #pragma unroll
    for (int i = 0; i < 8; ++i) {
      int gn = cb + w*64 + i*8 + lrow;                       // may overrun cend (padded)
      const unsigned short* src = Cb + (size_t)gn * D + kb*KCF + su*8;
      unsigned short* dst = ch + buf*(256*64) + (w*64 + i*8)*64;
      async16(src, dst);
    }
  };

  f32x16 zf;
  #pragma unroll
  for (int e = 0; e < 16; ++e) zf[e] = 0.f;

  const int nsteps = (cend - cbase0 + NTF - 1) / NTF;
  int b = 0;
  STAGE(0, 0, cbase0);
  __syncthreads();            // drain prologue

  for (int nt = 0; nt < nsteps; ++nt) {
    const int cbase = cbase0 + nt * NTF;
    f32x16 acc[2];
    acc[0] = zf; acc[1] = zf;

    for (int kb = 0; kb < D/KCF; ++kb) {
      if (kb + 1 < D/KCF) {
        STAGE(b^1, kb+1, cbase);
        asm volatile("s_waitcnt vmcnt(9)" ::: "memory");
      } else if (nt + 1 < nsteps) {
        STAGE(b^1, 0, cbase + NTF);
        asm volatile("s_waitcnt vmcnt(9)" ::: "memory");
      } else {
        asm volatile("s_waitcnt vmcnt(0)" ::: "memory");
      }
      __builtin_amdgcn_s_barrier();
      __builtin_amdgcn_sched_barrier(0);

      const unsigned short* qb  = qh + b*(32*64);
      const unsigned short* cbf = ch + b*(256*64);
      #pragma unroll
      for (int ks = 0; ks < 4; ++ks) {
        const int u = 2*ks + half;
        s16x8 qf, cf[2];
        {
          int r = l31;
          qf = *(const s16x8*)(qb + r*64 + (u ^ (r & 7))*8);
        }
        #pragma unroll
        for (int ct = 0; ct < 2; ++ct) {
          int c = w*64 + ct*32 + l31;
          cf[ct] = *(const s16x8*)(cbf + c*64 + (u ^ (c & 7))*8);
        }
        #pragma unroll
        for (int ct = 0; ct < 2; ++ct)
          acc[ct] = __builtin_amdgcn_mfma_f32_32x32x16_bf16(qf, cf[ct], acc[ct], 0, 0, 0);
      }
      asm volatile("s_waitcnt lgkmcnt(0)" ::: "memory");
      __builtin_amdgcn_s_barrier();
      __builtin_amdgcn_sched_barrier(0);
      b ^= 1;
    }

    // epilogue: s = c2 - 2*dot -> dl (4 rounds of 8 rows); per-lane register filter
    float c2v[2]; int vld[2];
    #pragma unroll
    for (int ct = 0; ct < 2; ++ct) {
      int gc = cbase + w*64 + ct*32 + l31;
      vld[ct] = (gc < cend);
      c2v[ct] = vld[ct] ? c2g[gc] : 0.f;
    }
    #pragma unroll
    for (int p = 0; p < 4; ++p) {
      // acc reg 4p+jj holds local row jj + 8p + 4*half
      #pragma unroll
      for (int jj = 0; jj < 4; ++jj)
        #pragma unroll
        for (int ct = 0; ct < 2; ++ct) {
          float a = acc[ct][4*p + jj];
          float s = c2v[ct] - 2.f * a;
          dl[(4*half + jj)*NTF + w*64 + ct*32 + l31] = vld[ct] ? s : INF;
        }
      __syncthreads();
      // wave w scans rows 8p+2w, 8p+2w+1 (slots 2w, 2w+1)
      #pragma unroll
      for (int s2 = 0; s2 < 2; ++s2) {
        const int g = 2*p + s2;
        const float q2u = q2w[g];
        #pragma unroll
        for (int j2 = 0; j2 < 4; ++j2) {
          float sv  = dl[(2*w + s2)*NTF + l + 64*j2];
          float d2v = fmaxf(q2u + sv, 0.f);            // INF stays INF
          unsigned int kbit = __float_as_uint(d2v);
          unsigned int ci = (kbit != 0x7f800000u) ? (unsigned)(cbase + 64*j2 + l)
                                                  : 0x7fffffffu;
          unsigned long long e = ((unsigned long long)kbit << 32) | ci;
          if (e < vv[g][TOPL-1]) {
            vv[g][TOPL-1] = e;
            #pragma unroll
            for (int t = TOPL-1; t > 0; --t) {
              unsigned long long lo = vv[g][t-1] < vv[g][t] ? vv[g][t-1] : vv[g][t];
              unsigned long long hi = vv[g][t-1] < vv[g][t] ? vv[g][t]   : vv[g][t-1];
              vv[g][t-1] = lo; vv[g][t] = hi;
            }
          }
        }
      }
      __syncthreads();
    }
  }

  // ---- end-of-chunk selection: pivot + compact + rank (per wave) ----
  // sel reuses dead qh/ch region: 2048 u64 per wave (max Ns = 320).
  unsigned long long* sel = (unsigned long long*)smem + (size_t)w * 2048;
  const unsigned long long mlt = (l == 0) ? 0ull : ((~0ull) >> (64 - l)); // lanes < me
  __syncthreads();   // everyone past the main loop before qh/ch reuse
  #pragma unroll
  for (int g = 0; g < 8; ++g) {
    // pivot key = max over lanes of key(vv[g][0]); guarantees >=64 survivors
    unsigned int pk = (unsigned int)(vv[g][0] >> 32);
    #pragma unroll
    for (int o = 1; o < 64; o <<= 1) {
      unsigned int other = (unsigned int)__shfl_xor((int)pk, o, 64);
      pk = (other > pk) ? other : pk;
    }
    int cnt = 0;
    #pragma unroll
    for (int t = 0; t < TOPL; ++t) cnt += ((unsigned int)(vv[g][t] >> 32) <= pk) ? 1 : 0;
    unsigned long long b0 = __ballot(cnt & 1);
    unsigned long long b1 = __ballot(cnt & 2);
    unsigned long long b2 = __ballot(cnt & 4);
    int pre = __popcll(b0 & mlt) + 2*__popcll(b1 & mlt) + 4*__popcll(b2 & mlt);
    int Ns  = __popcll(b0) + 2*__popcll(b1) + 4*__popcll(b2);
    #pragma unroll
    for (int t = 0; t < TOPL; ++t)
      if (t < cnt) sel[pre + t] = vv[g][t];
    asm volatile("s_waitcnt lgkmcnt(0)" ::: "memory");
    __builtin_amdgcn_sched_barrier(0);
    int rk[TOPL];
    #pragma unroll
    for (int t = 0; t < TOPL; ++t) rk[t] = 0;
    for (int j = 0; j < Ns; ++j) {
      unsigned long long e = sel[j];
      #pragma unroll
      for (int t = 0; t < TOPL; ++t) rk[t] += (e < vv[g][t]) ? 1 : 0;
    }
    int gq = mbase + 8*(g>>1) + 2*w + (g&1);
    if (gq < n1) {
      #pragma unroll
      for (int t = 0; t < TOPL; ++t)
        if (t < cnt && rk[t] < KSEL) {
          size_t o = ((size_t)gq * nc + chunkid) * KSEL + rk[t];
          tkd[o] = __uint_as_float((unsigned int)(vv[g][t] >> 32));
          tki[o] = (int)(unsigned int)(vv[g][t] & 0xffffffffu);
        }
    }
  }
}

// ---------------- Phase 1 (fallback): R4 in-kernel-conversion 3-pass ----------------
__global__ __launch_bounds__(NTH) void knn_phase1_cvt_kernel(
    const float* __restrict__ Q, const float* __restrict__ C,
    const float* __restrict__ q2g, const float* __restrict__ c2g,
    float* __restrict__ tkd, int* __restrict__ tki,
    int n1, int n2, int chunk, int nc)
{
  extern __shared__ char smem[];
  unsigned short* qh = (unsigned short*)smem;
  unsigned short* ql = qh + 64*64;
  unsigned short* ch = ql + 64*64;
  unsigned short* cl = ch + 512*64;
  float* dl = (float*)(smem + 147456);

  const int tid  = threadIdx.x;
  const int w    = tid >> 6;
  const int l    = tid & 63;
  const int l31  = l & 31;
  const int half = l >> 5;
  const int mbase   = blockIdx.x * MT;
  const int chunkid = blockIdx.y;
  const int cbase0  = chunkid * chunk;
  const int cend    = min(cbase0 + chunk, n2);

  float q2w[8];
  #pragma unroll
  for (int g = 0; g < 8; ++g) q2w[g] = q2g[min(mbase + g*8 + w, n1 - 1)];

  float listd[8]; int listi[8]; float wd4[8]; int wi4[8];
  #pragma unroll
  for (int g = 0; g < 8; ++g) { listd[g]=INF; listi[g]=0x7fffffff; wd4[g]=INF; wi4[g]=0x7fffffff; }

  const int srow = tid >> 3;
  const int sk8  = (tid & 7) * 8;
  const int su   = (tid & 7);

  float4 cva[8][2], qva[2];
  auto LOADR = [&](int kb, int cb) {
    {
      int gr = min(mbase + srow, n1 - 1);
      const float4* p = (const float4*)(Q + (size_t)gr * D + kb*KC + sk8);
      qva[0] = p[0]; qva[1] = p[1];
    }
    #pragma unroll
    for (int r = 0; r < 8; ++r) {
      int gn = cb + srow + 64*r;
      if (gn < cend) {
        const float4* p = (const float4*)(C + (size_t)gn * D + kb*KC + sk8);
        cva[r][0] = p[0]; cva[r][1] = p[1];
      } else {
        cva[r][0] = make_float4(0.f,0.f,0.f,0.f);
        cva[r][1] = make_float4(0.f,0.f,0.f,0.f);
      }
    }
  };
  auto STORE = [&]() {
    int4 hi, lo;
    {
      int idx = srow*64 + (su ^ (srow & 7))*8;
      cvt8(qva[0], qva[1], hi, lo);
      *(int4*)(qh + idx) = hi; *(int4*)(ql + idx) = lo;
    }
    #pragma unroll
    for (int r = 0; r < 8; ++r) {
      int row = srow + 64*r;
      int idx = row*64 + (su ^ (row & 7))*8;
      cvt8(cva[r][0], cva[r][1], hi, lo);
      *(int4*)(ch + idx) = hi; *(int4*)(cl + idx) = lo;
    }
  };

  f32x16 zf;
  #pragma unroll
  for (int e = 0; e < 16; ++e) zf[e] = 0.f;

  const int nsteps = (cend - cbase0 + NT - 1) / NT;
  LOADR(0, cbase0);

  for (int nt = 0; nt < nsteps; ++nt) {
    const int cbase = cbase0 + nt * NT;
    f32x16 acc[2][2];
    #pragma unroll
    for (int rt = 0; rt < 2; ++rt)
      #pragma unroll
      for (int ct = 0; ct < 2; ++ct) acc[rt][ct] = zf;

    for (int kb = 0; kb < D/KC; ++kb) {
      __syncthreads();
      STORE();
      __syncthreads();
      if (kb + 1 < D/KC)        LOADR(kb + 1, cbase);
      else if (nt + 1 < nsteps) LOADR(0, cbase + NT);

      #pragma unroll
      for (int ks = 0; ks < 4; ++ks) {
        const int u = 2*ks + half;
        s16x8 qf[2][2], cf[2][2];
        #pragma unroll
        for (int rt = 0; rt < 2; ++rt) {
          int r = rt*32 + l31;
          int idx = r*64 + (u ^ (r & 7))*8;
          qf[rt][0] = *(const s16x8*)(qh + idx);
          qf[rt][1] = *(const s16x8*)(ql + idx);
        }
        #pragma unroll
        for (int ct = 0; ct < 2; ++ct) {
          int c = w*64 + ct*32 + l31;
          int idx = c*64 + (u ^ (c & 7))*8;
          cf[ct][0] = *(const s16x8*)(ch + idx);
          cf[ct][1] = *(const s16x8*)(cl + idx);
        }
        #pragma unroll
        for (int rt = 0; rt < 2; ++rt)
          #pragma unroll
          for (int ct = 0; ct < 2; ++ct) {
            acc[rt][ct] = __builtin_amdgcn_mfma_f32_32x32x16_bf16(qf[rt][0], cf[ct][0], acc[rt][ct], 0, 0, 0);
            acc[rt][ct] = __builtin_amdgcn_mfma_f32_32x32x16_bf16(qf[rt][0], cf[ct][1], acc[rt][ct], 0, 0, 0);
            acc[rt][ct] = __builtin_amdgcn_mfma_f32_32x32x16_bf16(qf[rt][1], cf[ct][0], acc[rt][ct], 0, 0, 0);
          }
      }
    }

    float c2v[2]; int vld[2];
    #pragma unroll
    for (int ct = 0; ct < 2; ++ct) {
      int gc = cbase + w*64 + ct*32 + l31;
      vld[ct] = (gc < cend);
      c2v[ct] = vld[ct] ? c2g[gc] : 0.f;
    }
    #pragma unroll
    for (int g = 0; g < 8; ++g) {
      const int rt = g >> 2, qq = g & 3;
      #pragma unroll
      for (int jj = 0; jj < 4; ++jj)
        #pragma unroll
        for (int ct = 0; ct < 2; ++ct) {
          float a = acc[rt][ct][4*qq + jj];
          float s = c2v[ct] - 2.f * a;
          dl[(4*half + jj)*512 + w*64 + ct*32 + l31] = vld[ct] ? s : INF;
        }
      __syncthreads();
      const float q2u = q2w[g];
      #pragma unroll
      for (int j2 = 0; j2 < 8; ++j2) {
        float sv = dl[w*512 + l + 64*j2];
        float dv = sqrtf(fmaxf(q2u + sv, 0.f));
        unsigned long long mask = __ballot(dv < wd4[g]);
        while (mask) {
          int L = __ffsll(mask) - 1; mask &= mask - 1;
          float dnew = __shfl(dv, L, 64);
          int ci = cbase + 64*j2 + L;
          if ((dnew < wd4[g]) || (dnew == wd4[g] && ci < wi4[g])) {
            bool isw = (l < 32) && (listd[g] == wd4[g]) && (listi[g] == wi4[g]);
            int wl = __ffsll(__ballot(isw)) - 1;
            if (l == wl) { listd[g] = dnew; listi[g] = ci; }
            worst_reduce((l < 32) ? listd[g] : -1.f,
                         (l < 32) ? listi[g] : -1, wd4[g], wi4[g]);
          }
        }
      }
      __syncthreads();
    }
  }

  #pragma unroll
  for (int g = 0; g < 8; ++g) {
    int gq = mbase + g*8 + w;
    float d = listd[g]; int i = listi[g];
    int rank = 0;
    #pragma unroll
    for (int j = 0; j < KSEL; ++j) {
      float dj = __shfl(listd[g], j, 64);
      int   ij = __shfl(listi[g], j, 64);
      rank += (dj < d) || (dj == d && ij < i);
    }
    if (l < 32 && gq < n1) {
      size_t o = ((size_t)gq * nc + chunkid) * KSEL + rank;
      tkd[o] = d; tki[o] = i;
    }
  }
}

// ---------------- Phase 2: merge + exact rescore + cosine ----------------
__global__ __launch_bounds__(256) void knn_phase2_kernel(
    const float* __restrict__ Q0, const float* __restrict__ Q1,
    const float* __restrict__ C0, const float* __restrict__ C1,
    const float* __restrict__ q2g, const float* __restrict__ c2g,
    const float* __restrict__ tkd, const int* __restrict__ tki,
    float* __restrict__ out, int n1, int n2, int nc)
{
  __shared__ float q0s[D], q1s[D];
  __shared__ float pd[256]; __shared__ int pi[256];
  __shared__ float nd[NSELMX]; __shared__ int ni[NSELMX];
  __shared__ float de[NSELMX];
  __shared__ int   fi[KSEL];
  __shared__ float cosj[KSEL];
  __shared__ float red0[4], red1[4], qn[2];

  const int q = blockIdx.x, tid = threadIdx.x;
  const int npool = nc * KSEL;
  const int nsel  = (NSELMX < npool) ? NSELMX : npool;

  if (tid < 128) ((float4*)q0s)[tid] = ((const float4*)(Q0 + (size_t)q*D))[tid];
  else           ((float4*)q1s)[tid-128] = ((const float4*)(Q1 + (size_t)q*D))[tid-128];
  if (tid < npool) { pd[tid] = tkd[(size_t)q*npool + tid]; pi[tid] = tki[(size_t)q*npool + tid]; }
  __syncthreads();

  float a0 = q0s[tid], b0 = q0s[tid+256], a1 = q1s[tid], b1 = q1s[tid+256];
  float s0 = a0*a0 + b0*b0, s1 = a1*a1 + b1*b1;
  #pragma unroll
  for (int o = 32; o > 0; o >>= 1) { s0 += __shfl_down(s0, o, 64); s1 += __shfl_down(s1, o, 64); }
  int lane = tid & 63, wid = tid >> 6;
  if (lane == 0) { red0[wid] = s0; red1[wid] = s1; }

  if (tid < npool) {
    float dm = pd[tid]; int im = pi[tid]; int rank = 0;
    for (int j = 0; j < npool; ++j) {
      float dj = pd[j]; int ij = pi[j];
      rank += (dj < dm) || (dj == dm && ij < im);
    }
    if (rank < nsel) { nd[rank] = dm; ni[rank] = im; }
  }
  __syncthreads();
  if (tid == 0) {
    qn[0] = fmaxf(sqrtf(red0[0]+red0[1]+red0[2]+red0[3]), CEPS);
    qn[1] = fmaxf(sqrtf(red1[0]+red1[1]+red1[2]+red1[3]), CEPS);
  }

  const float q2q = q2g[q];
  const int ll = tid & 7;
  for (int base = 0; base < NSELMX; base += 32) {
    int g = base + (tid >> 3);
    if (g < nsel) {
      int ix = ni[g];
      bool okx = (ix >= 0 && ix < n2);
      int ixc = okx ? ix : 0;
      const float4* r0  = (const float4*)(C0 + (size_t)ixc * D);
      const float4* q04 = (const float4*)q0s;
      float dot = 0.f;
      #pragma unroll
      for (int r = 0; r < 16; ++r) {
        float4 v = r0[r*8 + ll], u = q04[r*8 + ll];
        dot = fmaf(v.x,u.x, fmaf(v.y,u.y, fmaf(v.z,u.z, fmaf(v.w,u.w, dot))));
      }
      #pragma unroll
      for (int o = 4; o > 0; o >>= 1) dot += __shfl_xor(dot, o, 64);
      if (ll == 0) de[g] = okx ? sqrtf(fmaxf(q2q + c2g[ixc] - 2.f*dot, 0.f)) : INF;
    }
  }
  __syncthreads();

  if (tid < nsel) {
    float dm = de[tid]; int im = ni[tid]; int rank = 0;
    for (int j = 0; j < nsel; ++j) {
      float dj = de[j]; int ij = ni[j];
      rank += (dj < dm) || (dj == dm && ij < im);
    }
    if (rank < KSEL) fi[rank] = im;
  }
  __syncthreads();

  const int g = tid >> 3;
  int ix = fi[g];
  ix = (ix >= 0 && ix < n2) ? ix : 0;
  const float4* r0  = (const float4*)(C0 + (size_t)ix * D);
  const float4* r1  = (const float4*)(C1 + (size_t)ix * D);
  const float4* q04 = (const float4*)q0s;
  const float4* q14 = (const float4*)q1s;
  float dot0 = 0.f, nn0 = 0.f, dot1 = 0.f, nn1 = 0.f;
  #pragma unroll
  for (int r = 0; r < 16; ++r) {
    int e4 = r*8 + ll;
    float4 v0 = r0[e4], qv0 = q04[e4];
    dot0 = fmaf(v0.x,qv0.x, fmaf(v0.y,qv0.y, fmaf(v0.z,qv0.z, fmaf(v0.w,qv0.w, dot0))));
    nn0  = fmaf(v0.x,v0.x,  fmaf(v0.y,v0.y,  fmaf(v0.z,v0.z,  fmaf(v0.w,v0.w,  nn0))));
    float4 v1 = r1[e4], qv1 = q14[e4];
    dot1 = fmaf(v1.x,qv1.x, fmaf(v1.y,qv1.y, fmaf(v1.z,qv1.z, fmaf(v1.w,qv1.w, dot1))));
    nn1  = fmaf(v1.x,v1.x,  fmaf(v1.y,v1.y,  fmaf(v1.z,v1.z,  fmaf(v1.w,v1.w,  nn1))));
  }
  #pragma unroll
  for (int o = 4; o > 0; o >>= 1) {
    dot0 += __shfl_xor(dot0, o, 64); nn0 += __shfl_xor(nn0, o, 64);
    dot1 += __shfl_xor(dot1, o, 64); nn1 += __shfl_xor(nn1, o, 64);
  }
  if (ll == 0) {
    float c0 = dot0 / (fmaxf(sqrtf(nn0), CEPS) * qn[0]);
    float c1 = dot1 / (fmaxf(sqrtf(nn1), CEPS) * qn[1]);
    float cv = (c0 > c1) ? c0 : c1;
    out[(size_t)q * KSEL + g] = cv;
    cosj[g] = cv;
  }
  __syncthreads();
  if (tid == 0) {
    float s = 0.f;
    #pragma unroll
    for (int j = 0; j < KSEL; ++j) s += cosj[j];
    out[(size_t)n1 * KSEL + q] = s * (1.f / KSEL);
  }
}

// ---------------- launch ----------------
extern "C" void kernel_launch(void* const* d_in, const int* in_sizes, int n_in,
                              void* d_out, int out_size, void* d_ws, size_t ws_size,
                              hipStream_t stream)
{
  const float* Q0 = (const float*)d_in[0];
  const float* Q1 = (const float*)d_in[1];
  const float* C0 = (const float*)d_in[2];
  const float* C1 = (const float*)d_in[3];
  const int n1 = in_sizes[0] / D;   // 2048
  const int n2 = in_sizes[2] / D;   // 50000
  float* out = (float*)d_out;
  if (n1 <= 0 || n2 <= 0) return;

  char* wsb = (char*)d_ws;
  size_t c2n = ((size_t)n2 + 127) & ~(size_t)127;
  size_t q2n = ((size_t)n1 + 127) & ~(size_t)127;

  size_t off_c2  = 0;
  size_t off_q2  = off_c2 + c2n*4;
  size_t off_tkd = off_q2 + q2n*4;
  size_t off_tki = off_tkd + (size_t)n1*NCF*KSEL*4;
  size_t off_cb  = (off_tki + (size_t)n1*NCF*KSEL*4 + 255) & ~(size_t)255;
  size_t off_qb  = off_cb + ((size_t)n2 + 512)*D*2;
  size_t need    = off_qb + (size_t)n1*D*2;
  bool fast = (ws_size >= need);

  if (fast) {
    float* c2  = (float*)(wsb + off_c2);
    float* q2  = (float*)(wsb + off_q2);
    float* tkd = (float*)(wsb + off_tkd);
    int*   tki = (int*)(wsb + off_tki);
    unsigned short* Cb = (unsigned short*)(wsb + off_cb);
    unsigned short* Qb = (unsigned short*)(wsb + off_qb);

    sumsq_cvt_kernel<<<(n2 + n1 + 3)/4, 256, 0, stream>>>(C0, Q0, c2, q2, Cb, Qb, n2, n1);

    const int chunk  = (n2 + NCF - 1) / NCF;
    const int mtiles = (n1 + MTF - 1) / MTF;
    (void)hipFuncSetAttribute((const void*)knn_phase1_bf_kernel,
                              hipFuncAttributeMaxDynamicSharedMemorySize, 81920);
    knn_phase1_bf_kernel<<<mtiles * NCF, NTHF, 81920, stream>>>(
        Qb, Cb, q2, c2, tkd, tki, n1, n2, chunk, NCF);
    knn_phase2_kernel<<<n1, 256, 0, stream>>>(Q0, Q1, C0, C1, q2, c2, tkd, tki, out, n1, n2, NCF);
  } else {
    float* wsf = (float*)d_ws;
    int nc = 8;
    while (nc > 1 && (c2n + q2n + (size_t)n1 * nc * KSEL * 2) * 4 > ws_size) nc >>= 1;
    float* c2  = wsf;
    float* q2  = wsf + c2n;
    float* tkd = wsf + c2n + q2n;
    int*   tki = (int*)(wsf + c2n + q2n + (size_t)n1 * nc * KSEL);

    rows_sumsq_kernel<<<(n2 + n1 + 3)/4, 256, 0, stream>>>(C0, Q0, c2, q2, n2, n1);
    const int chunk  = (n2 + nc - 1) / nc;
    const int mtiles = (n1 + MT - 1) / MT;
    (void)hipFuncSetAttribute((const void*)knn_phase1_cvt_kernel,
                              hipFuncAttributeMaxDynamicSharedMemorySize, 163840);
    knn_phase1_cvt_kernel<<<dim3(mtiles, nc), NTH, 163840, stream>>>(
        Q0, C0, q2, c2, tkd, tki, n1, n2, chunk, nc);
    knn_phase2_kernel<<<n1, 256, 0, stream>>>(Q0, Q1, C0, C1, q2, c2, tkd, tki, out, n1, n2, nc);
  }
}